// Round 7
// baseline (552.587 us; speedup 1.0000x reference)
//
#include <hip/hip_runtime.h>
#include <hip/hip_bf16.h>
#include <cstdint>

// Problem constants
#define PB 4
#define PS 2048
#define PE 1024
#define PH 16
#define PD 64
#define PM (PB * PS)      // 8192 rows

typedef __attribute__((ext_vector_type(8))) short short8;   // 8 bf16 (4 VGPR)
typedef __attribute__((ext_vector_type(4))) float f32x4;

#define MFMA16 __builtin_amdgcn_mfma_f32_16x16x32_bf16

#define GLOAD_LDS(gp, lp) __builtin_amdgcn_global_load_lds(                    \
    (const __attribute__((address_space(1))) void*)(gp),                       \
    (__attribute__((address_space(3))) void*)(lp), 16, 0, 0)

// fp32 -> bf16 round-to-nearest-even (finite inputs)
__device__ inline unsigned short bf16rn(float x) {
    unsigned u = __builtin_bit_cast(unsigned, x);
    u += 0x7FFFu + ((u >> 16) & 1u);
    return (unsigned short)(u >> 16);
}
__device__ inline float bf16tof(unsigned short h) {
    unsigned u = ((unsigned)h) << 16;
    return __builtin_bit_cast(float, u);
}
__device__ inline void split2(float x, unsigned short& h, unsigned short& l) {
    h = bf16rn(x);
    l = bf16rn(x - bf16tof(h));
}

// ---------------------------------------------------------------------------
// split_mat: fp32 matrix -> bf16 hi/lo planes (row-major, same shape)
// ---------------------------------------------------------------------------
__global__ __launch_bounds__(256)
void split_mat(const float* __restrict__ src, unsigned short* __restrict__ hi,
               unsigned short* __restrict__ lo, int n4)
{
    int i = blockIdx.x * 256 + threadIdx.x;
    if (i >= n4) return;
    float4 f = ((const float4*)src)[i];
    ushort4 h, l;
    split2(f.x, h.x, l.x); split2(f.y, h.y, l.y);
    split2(f.z, h.z, l.z); split2(f.w, h.w, l.w);
    ((ushort4*)hi)[i] = h;
    ((ushort4*)lo)[i] = l;
}

// ---------------------------------------------------------------------------
// Plane-fed split-bf16 MFMA NT GEMM v2:
// BK=32 per step; hi|lo interleaved in one 128-B LDS row (hi = bytes 0..63,
// lo = 64..127), XOR-swizzled byte ^ (row&7)<<4 (proven layout). Double-
// buffered (2 x [A 16KB + B 16KB] = 64KB); per K-step: issue next-step
// global_load_lds, compute current, one barrier. Compensated product
// AhBh + AhBl + AlBh (~2^-17 rel).
// Waves: 2x2 of 64x64; lane(lq,lg) owns C[16mt+4lg+j][16nt+lq] per subtile.
// MODE 0: fp32 C[m*N+n]            (optional RELU)
// MODE 1: fp32 at BHSD index       (Q projection)
// MODE 3: bf16 hi/lo planes at BHSD index      (K projection)
// MODE 4: bf16 hi/lo planes at BHDS (V^T) index + PV seq permutation
// MODE 5: bf16 hi/lo planes row-major [M][N]   (h1, with RELU)
// MODE 6: neuromod combine -> bf16 hi/lo planes [M][N] (attnf)
// ---------------------------------------------------------------------------
template<int MODE, bool RELU>
__global__ __launch_bounds__(256, 2)
void gemm_pl(const unsigned short* __restrict__ Ahi,
             const unsigned short* __restrict__ Alo,
             const unsigned short* __restrict__ Bhi,
             const unsigned short* __restrict__ Blo,
             const float* __restrict__ bias, float* __restrict__ C,
             unsigned short* __restrict__ Ohi, unsigned short* __restrict__ Olo,
             int M, int N, int K,
             const float* __restrict__ attn,
             const float* __restrict__ g0, const float* __restrict__ g1,
             const float* __restrict__ g2, const float* __restrict__ g3,
             const float* __restrict__ asc, const float* __restrict__ abi)
{
    __shared__ int4 ldsq[4096];                 // 64 KB: 2 bufs x (A16K + B16K)
    char* const lds = (char*)ldsq;

    const int tid  = threadIdx.x;
    const int lane = tid & 63;
    const int w    = tid >> 6;
    const int lq   = lane & 15;
    const int lg   = lane >> 4;
    const int wm   = (w >> 1) * 64;
    const int wn   = (w & 1) * 64;
    const int m0   = blockIdx.x * 128;
    const int n0   = blockIdx.y * 128;

    // staging role: wave 0,1 -> A rows 0-63 / 64-127; wave 2,3 -> B.
    const int smat   = w >> 1;                  // 0=A, 1=B
    const int chunk0 = (w & 1) * 8;             // first 1KB chunk (16/mat)
    const unsigned short* const sHi =
        smat ? Bhi + (size_t)n0 * K : Ahi + (size_t)m0 * K;
    const unsigned short* const sLo =
        smat ? Blo + (size_t)n0 * K : Alo + (size_t)m0 * K;
    const int lrow = lane >> 3;                 // row within 8-row chunk
    const int lc   = (lane & 7) ^ lrow;         // pre-swizzled logical slot
    const unsigned short* const sP = (lc < 4) ? sHi : sLo;
    const int selem = (lc & 3) * 8;             // element offset within BK=32

    auto ISSUE = [&](int k0, int bufn) {
        #pragma unroll
        for (int r = 0; r < 8; ++r) {
            const int c   = chunk0 + r;
            const int row = c * 8 + lrow;
            GLOAD_LDS(sP + (size_t)row * K + k0 + selem,
                      lds + bufn * 32768 + smat * 16384 + c * 1024 + 16 * lane);
        }
    };

    f32x4 acc[4][4];
    #pragma unroll
    for (int mt = 0; mt < 4; ++mt)
        #pragma unroll
        for (int nt = 0; nt < 4; ++nt)
            acc[mt][nt] = (f32x4){0.f, 0.f, 0.f, 0.f};

    ISSUE(0, 0);
    __syncthreads();
    int buf = 0;
    for (int k0 = 0; k0 < K; k0 += 32) {
        if (k0 + 32 < K) ISSUE(k0 + 32, buf ^ 1);

        const char* const L = lds + buf * 32768;
        short8 afh[4], afl[4];
        #pragma unroll
        for (int mt = 0; mt < 4; ++mt) {
            const int row = wm + 16 * mt + lq;
            const int swz = (row & 7) << 4;
            afh[mt] = *(const short8*)(L + row * 128 + ((16 * lg) ^ swz));
            afl[mt] = *(const short8*)(L + row * 128 + ((64 + 16 * lg) ^ swz));
        }
        #pragma unroll
        for (int nt = 0; nt < 4; ++nt) {
            const int row = wn + 16 * nt + lq;
            const int swz = (row & 7) << 4;
            short8 bfh = *(const short8*)(L + 16384 + row * 128 + ((16 * lg) ^ swz));
            short8 bfl = *(const short8*)(L + 16384 + row * 128 + ((64 + 16 * lg) ^ swz));
            #pragma unroll
            for (int mt = 0; mt < 4; ++mt) {
                acc[mt][nt] = MFMA16(afh[mt], bfh, acc[mt][nt], 0, 0, 0);
                acc[mt][nt] = MFMA16(afh[mt], bfl, acc[mt][nt], 0, 0, 0);
                acc[mt][nt] = MFMA16(afl[mt], bfh, acc[mt][nt], 0, 0, 0);
            }
        }
        __syncthreads();
        buf ^= 1;
    }

    float gain = 0.f, ascv = 0.f, abiv = 0.f;
    if (MODE == 6) {
        gain = 0.25f * (*g0 + *g1 + *g2 + *g3);
        ascv = *asc;
        abiv = *abi;
    }

    #pragma unroll
    for (int nt = 0; nt < 4; ++nt) {
        const int n  = n0 + wn + 16 * nt + lq;
        const float bv = bias[n];
        #pragma unroll
        for (int mt = 0; mt < 4; ++mt) {
            #pragma unroll
            for (int j = 0; j < 4; ++j) {
                const int m = m0 + wm + 16 * mt + 4 * lg + j;
                float v = acc[mt][nt][j] + bv;
                if (RELU) v = fmaxf(v, 0.f);
                if (MODE == 0) {
                    C[(size_t)m * N + n] = v;
                } else if (MODE == 1) {
                    const int b = m >> 11, s = m & 2047;
                    const int h = n >> 6, d = n & 63;
                    C[((size_t)(b * PH + h) * PS + s) * PD + d] = v;
                } else if (MODE == 3) {
                    const int b = m >> 11, s = m & 2047;
                    const int h = n >> 6, d = n & 63;
                    const size_t idx = ((size_t)(b * PH + h) * PS + s) * PD + d;
                    unsigned short hh, ll;
                    split2(v, hh, ll);
                    Ohi[idx] = hh; Olo[idx] = ll;
                } else if (MODE == 4) {
                    const int b = m >> 11;
                    const int h = n >> 6, d = n & 63;
                    const int scol = (m & 2047 & ~63) + ((mt & 1) << 5)
                                   + (lg << 3) + ((mt >> 1) << 2) + j;
                    const size_t idx = ((size_t)(b * PH + h) * PD + d) * PS + scol;
                    unsigned short hh, ll;
                    split2(v, hh, ll);
                    Ohi[idx] = hh; Olo[idx] = ll;
                } else if (MODE == 5) {
                    const size_t idx = (size_t)m * N + n;
                    unsigned short hh, ll;
                    split2(v, hh, ll);
                    Ohi[idx] = hh; Olo[idx] = ll;
                } else { // MODE 6
                    const int b = m >> 11, s = m & 2047;
                    const int h = n >> 6, d = n & 63;
                    const float av = attn[((size_t)(b * PH + h) * PS + s) * PD + d];
                    const float o = (av * ascv + abiv) * (1.f + v * gain);
                    const size_t idx = (size_t)m * N + n;
                    unsigned short hh, ll;
                    split2(o, hh, ll);
                    Ohi[idx] = hh; Olo[idx] = ll;
                }
            }
        }
    }
}

// ---------------------------------------------------------------------------
// fp32-fed split-bf16 MFMA NT GEMM (fallback path, round-5 proven).
// ---------------------------------------------------------------------------
template<int MODE, bool RELU>
__global__ __launch_bounds__(256, 2)
void gemm_nt(const float* __restrict__ A, const float* __restrict__ Bw,
             const float* __restrict__ bias, float* __restrict__ C,
             unsigned short* __restrict__ Ohi, unsigned short* __restrict__ Olo,
             int M, int N, int K,
             const float* __restrict__ attn,
             const float* __restrict__ g0, const float* __restrict__ g1,
             const float* __restrict__ g2, const float* __restrict__ g3,
             const float* __restrict__ asc, const float* __restrict__ abi)
{
    __shared__ int4 ldsq[4096];
    char* const lds = (char*)ldsq;

    const int tid  = threadIdx.x;
    const int lane = tid & 63;
    const int w    = tid >> 6;
    const int lq   = lane & 15;
    const int lg   = lane >> 4;
    const int wm   = (w >> 1) * 64;
    const int wn   = (w & 1) * 64;
    const int m0   = blockIdx.x * 128;
    const int n0   = blockIdx.y * 128;

    const int irow = tid >> 3;
    const int ic8  = (tid & 7) * 8;
    const int woff = (ic8 * 2);

    f32x4 acc[4][4];
    #pragma unroll
    for (int mt = 0; mt < 4; ++mt)
        #pragma unroll
        for (int nt = 0; nt < 4; ++nt)
            acc[mt][nt] = (f32x4){0.f, 0.f, 0.f, 0.f};

    for (int k0 = 0; k0 < K; k0 += 64) {
        #pragma unroll
        for (int mat = 0; mat < 2; ++mat) {
            const float* const src = mat ? Bw : A;
            const int rbase = mat ? n0 : m0;
            const int pbase = mat ? 32768 : 0;
            #pragma unroll
            for (int r = 0; r < 4; ++r) {
                const int row = irow + 32 * r;
                const float* p = src + (size_t)(rbase + row) * K + k0 + ic8;
                float4 f0 = *(const float4*)p;
                float4 f1 = *(const float4*)(p + 4);
                short8 vh, vl;
                {
                    unsigned short h, l;
                    split2(f0.x, h, l); vh[0] = (short)h; vl[0] = (short)l;
                    split2(f0.y, h, l); vh[1] = (short)h; vl[1] = (short)l;
                    split2(f0.z, h, l); vh[2] = (short)h; vl[2] = (short)l;
                    split2(f0.w, h, l); vh[3] = (short)h; vl[3] = (short)l;
                    split2(f1.x, h, l); vh[4] = (short)h; vl[4] = (short)l;
                    split2(f1.y, h, l); vh[5] = (short)h; vl[5] = (short)l;
                    split2(f1.z, h, l); vh[6] = (short)h; vl[6] = (short)l;
                    split2(f1.w, h, l); vh[7] = (short)h; vl[7] = (short)l;
                }
                const int off = row * 128 + (woff ^ ((row & 7) << 4));
                *(short8*)(lds + pbase + off)         = vh;
                *(short8*)(lds + pbase + 16384 + off) = vl;
            }
        }
        __syncthreads();

        #pragma unroll
        for (int kh = 0; kh < 2; ++kh) {
            short8 afh[4], afl[4];
            #pragma unroll
            for (int mt = 0; mt < 4; ++mt) {
                const int row = wm + 16 * mt + lq;
                const int off = row * 128 + ((kh * 64 + 16 * lg) ^ ((row & 7) << 4));
                afh[mt] = *(const short8*)(lds + off);
                afl[mt] = *(const short8*)(lds + 16384 + off);
            }
            #pragma unroll
            for (int nt = 0; nt < 4; ++nt) {
                const int row = wn + 16 * nt + lq;
                const int off = row * 128 + ((kh * 64 + 16 * lg) ^ ((row & 7) << 4));
                short8 bfh = *(const short8*)(lds + 32768 + off);
                short8 bfl = *(const short8*)(lds + 49152 + off);
                #pragma unroll
                for (int mt = 0; mt < 4; ++mt) {
                    acc[mt][nt] = MFMA16(afh[mt], bfh, acc[mt][nt], 0, 0, 0);
                    acc[mt][nt] = MFMA16(afh[mt], bfl, acc[mt][nt], 0, 0, 0);
                    acc[mt][nt] = MFMA16(afl[mt], bfh, acc[mt][nt], 0, 0, 0);
                }
            }
        }
        __syncthreads();
    }

    float gain = 0.f, ascv = 0.f, abiv = 0.f;
    if (MODE == 2) {
        gain = 0.25f * (*g0 + *g1 + *g2 + *g3);
        ascv = *asc;
        abiv = *abi;
    }

    #pragma unroll
    for (int nt = 0; nt < 4; ++nt) {
        const int n  = n0 + wn + 16 * nt + lq;
        const float bv = bias[n];
        #pragma unroll
        for (int mt = 0; mt < 4; ++mt) {
            #pragma unroll
            for (int j = 0; j < 4; ++j) {
                const int m = m0 + wm + 16 * mt + 4 * lg + j;
                float v = acc[mt][nt][j] + bv;
                if (RELU) v = fmaxf(v, 0.f);
                if (MODE == 0) {
                    C[(size_t)m * N + n] = v;
                } else if (MODE == 1) {
                    const int b = m >> 11, s = m & 2047;
                    const int h = n >> 6, d = n & 63;
                    C[((size_t)(b * PH + h) * PS + s) * PD + d] = v;
                } else if (MODE == 3) {
                    const int b = m >> 11, s = m & 2047;
                    const int h = n >> 6, d = n & 63;
                    const size_t idx = ((size_t)(b * PH + h) * PS + s) * PD + d;
                    unsigned short hh, ll;
                    split2(v, hh, ll);
                    Ohi[idx] = hh; Olo[idx] = ll;
                } else if (MODE == 4) {
                    const int b = m >> 11;
                    const int h = n >> 6, d = n & 63;
                    const int scol = (m & 2047 & ~63) + ((mt & 1) << 5)
                                   + (lg << 3) + ((mt >> 1) << 2) + j;
                    const size_t idx = ((size_t)(b * PH + h) * PD + d) * PS + scol;
                    unsigned short hh, ll;
                    split2(v, hh, ll);
                    Ohi[idx] = hh; Olo[idx] = ll;
                } else { // MODE 2
                    const int b = m >> 11, s = m & 2047;
                    const int h = n >> 6, d = n & 63;
                    const float av = attn[((size_t)(b * PH + h) * PS + s) * PD + d];
                    C[(size_t)m * N + n] = (av * ascv + abiv) * (1.f + v * gain);
                }
            }
        }
    }
}

// ---------------------------------------------------------------------------
// MFMA flash attention v4: single 32KB LDS buffer -> 4 blocks/CU (TLP hides
// load latency + dependent-MFMA chains); P kept in SINGLE bf16 (PV = 2 MFMA:
// Vhi.P + Vlo.P). QK^T stays 3-term compensated. Staging via global_load_lds
// with pre-swizzled global source (v3-proven). 2 barriers/tile.
// ---------------------------------------------------------------------------
__global__ __launch_bounds__(256, 4)
void flash_mfma(const float* qf,
                const unsigned short* __restrict__ khi,
                const unsigned short* __restrict__ klo,
                const unsigned short* __restrict__ vthi,
                const unsigned short* __restrict__ vtlo,
                float* attn)
{
    __shared__ int4 ldsv[2048];                    // 32 KB: 4 planes x 8KB
    char* const ldsb = (char*)ldsv;

    const int tid  = threadIdx.x;
    const int lane = tid & 63;
    const int w    = tid >> 6;
    const int bh   = blockIdx.z * PH + blockIdx.y;
    const int lq   = lane & 15;
    const int lg   = lane >> 4;
    const int q0   = blockIdx.x * 128 + w * 32;

    const size_t kbase = (size_t)bh * PS * PD;   // K rows   [S][D]
    const size_t vbase = (size_t)bh * PD * PS;   // V^T rows [D][S] (permuted)

    const unsigned short* const gp =
        (w == 0) ? khi + kbase :
        (w == 1) ? klo + kbase :
        (w == 2) ? vthi + vbase :
                   vtlo + vbase;
    const bool isK = (w < 2);
    const int scol8 = (((lane & 7) ^ (lane >> 3)) << 3);   // pre-swizzled col
    const int lrow8 = lane >> 3;

    auto ISSUE = [&](int kt) {
        #pragma unroll
        for (int r = 0; r < 8; ++r) {
            const int row = r * 8 + lrow8;
            const size_t goff = isK ? (size_t)(kt + row) * PD + scol8
                                    : (size_t)row * PS + kt + scol8;
            GLOAD_LDS(gp + goff, ldsb + w * 8192 + r * 1024 + 16 * lane);
        }
    };

    // ---- Q fragments (scale 1/8 folded in), 2 q-subtiles per wave
    short8 qh[2][2], ql[2][2];
    #pragma unroll
    for (int u = 0; u < 2; ++u) {
        const float* qp = qf + ((size_t)bh * PS + q0 + 16 * u + lq) * PD + 8 * lg;
        #pragma unroll
        for (int t = 0; t < 2; ++t)
            #pragma unroll
            for (int b = 0; b < 8; ++b) {
                float x = qp[t * 32 + b] * 0.125f;
                unsigned short h, l;
                split2(x, h, l);
                qh[u][t][b] = (short)h;
                ql[u][t][b] = (short)l;
            }
    }

    f32x4 ot[2][4];
    #pragma unroll
    for (int u = 0; u < 2; ++u)
        #pragma unroll
        for (int mt = 0; mt < 4; ++mt)
            ot[u][mt] = (f32x4){0.f, 0.f, 0.f, 0.f};
    float m_run[2] = {-3.0e38f, -3.0e38f};
    float l_run[2] = {0.f, 0.f};

    for (int kti = 0; kti < PS / 64; ++kti) {
        ISSUE(kti * 64);
        __syncthreads();            // drains gload vmcnt -> tile ready

        // ---- S^T tiles for both q-subtiles (3-term compensated)
        f32x4 st[2][4];
        #pragma unroll
        for (int mt = 0; mt < 4; ++mt) {
            const int row = 16 * mt + lq;
            const int swz = (row & 7) << 4;
            const char* kr = ldsb + row * 128;
            short8 ah0 = *(const short8*)(kr + ((16 * lg) ^ swz));
            short8 ah1 = *(const short8*)(kr + ((64 + 16 * lg) ^ swz));
            short8 al0 = *(const short8*)(kr + 8192 + ((16 * lg) ^ swz));
            short8 al1 = *(const short8*)(kr + 8192 + ((64 + 16 * lg) ^ swz));
            #pragma unroll
            for (int u = 0; u < 2; ++u) {
                f32x4 acc = {0.f, 0.f, 0.f, 0.f};
                acc = MFMA16(ah0, qh[u][0], acc, 0, 0, 0);
                acc = MFMA16(ah1, qh[u][1], acc, 0, 0, 0);
                acc = MFMA16(ah0, ql[u][0], acc, 0, 0, 0);
                acc = MFMA16(ah1, ql[u][1], acc, 0, 0, 0);
                acc = MFMA16(al0, qh[u][0], acc, 0, 0, 0);
                acc = MFMA16(al1, qh[u][1], acc, 0, 0, 0);
                st[u][mt] = acc;
            }
        }

        // ---- online softmax + P pack (single bf16), per q-subtile
        short8 pb[2][2];
        #pragma unroll
        for (int u = 0; u < 2; ++u) {
            float pmax = -3.0e38f;
            #pragma unroll
            for (int mt = 0; mt < 4; ++mt)
                #pragma unroll
                for (int j = 0; j < 4; ++j)
                    pmax = fmaxf(pmax, st[u][mt][j]);
            pmax = fmaxf(pmax, __shfl_xor(pmax, 16));
            pmax = fmaxf(pmax, __shfl_xor(pmax, 32));
            float mnew = fmaxf(m_run[u], pmax);
            float corr = __expf(m_run[u] - mnew);
            float psum = 0.f;
            #pragma unroll
            for (int mt = 0; mt < 4; ++mt)
                #pragma unroll
                for (int j = 0; j < 4; ++j) {
                    float p = __expf(st[u][mt][j] - mnew);
                    psum += p;
                    st[u][mt][j] = p;
                }
            psum += __shfl_xor(psum, 16);
            psum += __shfl_xor(psum, 32);
            l_run[u] = l_run[u] * corr + psum;
            m_run[u] = mnew;
            #pragma unroll
            for (int mt = 0; mt < 4; ++mt)
                #pragma unroll
                for (int j = 0; j < 4; ++j)
                    ot[u][mt][j] *= corr;
            #pragma unroll
            for (int b = 0; b < 8; ++b) {
                const int mt0 = (b >> 2) << 1;
                pb[u][0][b] = (short)bf16rn(st[u][mt0][b & 3]);
                pb[u][1][b] = (short)bf16rn(st[u][mt0 + 1][b & 3]);
            }
        }

        // ---- O^T += V^T . P^T   (V hi/lo, P single: 2 MFMA each)
        #pragma unroll
        for (int t = 0; t < 2; ++t) {
            #pragma unroll
            for (int mt = 0; mt < 4; ++mt) {
                const int row = 16 * mt + lq;
                const int swz = (row & 7) << 4;
                const char* vr = ldsb + 16384 + row * 128;
                short8 vh = *(const short8*)(vr + ((t * 64 + 16 * lg) ^ swz));
                short8 vl = *(const short8*)(vr + 8192 + ((t * 64 + 16 * lg) ^ swz));
                #pragma unroll
                for (int u = 0; u < 2; ++u) {
                    ot[u][mt] = MFMA16(vh, pb[u][t], ot[u][mt], 0, 0, 0);
                    ot[u][mt] = MFMA16(vl, pb[u][t], ot[u][mt], 0, 0, 0);
                }
            }
        }

        __syncthreads();            // all reads done before next tile's ISSUE
    }

    // ---- epilogue: attn[bh][q0+16u+lq][d], d = 16*mt + 4*lg + j
    #pragma unroll
    for (int u = 0; u < 2; ++u) {
        const float inv = 1.f / l_run[u];
        float* op = attn + ((size_t)bh * PS + q0 + 16 * u + lq) * PD + 4 * lg;
        #pragma unroll
        for (int mt = 0; mt < 4; ++mt) {
            float4 o;
            o.x = ot[u][mt][0] * inv; o.y = ot[u][mt][1] * inv;
            o.z = ot[u][mt][2] * inv; o.w = ot[u][mt][3] * inv;
            *(float4*)(op + 16 * mt) = o;
        }
    }
}

// ---------------------------------------------------------------------------
extern "C" void kernel_launch(void* const* d_in, const int* in_sizes, int n_in,
                              void* d_out, int out_size, void* d_ws, size_t ws_size,
                              hipStream_t stream)
{
    const float* query = (const float*)d_in[0];
    const float* Wq  = (const float*)d_in[1];  const float* bq  = (const float*)d_in[2];
    const float* Wk  = (const float*)d_in[3];  const float* bk  = (const float*)d_in[4];
    const float* Wv  = (const float*)d_in[5];  const float* bv  = (const float*)d_in[6];
    const float* Wo  = (const float*)d_in[7];  const float* bo  = (const float*)d_in[8];
    const float* Wm1 = (const float*)d_in[9];  const float* bm1 = (const float*)d_in[10];
    const float* Wm2 = (const float*)d_in[11]; const float* bm2 = (const float*)d_in[12];
    const float* dop = (const float*)d_in[13];
    const float* ser = (const float*)d_in[14];
    const float* nor = (const float*)d_in[15];
    const float* ach = (const float*)d_in[16];
    const float* asc = (const float*)d_in[17];
    const float* abi = (const float*)d_in[18];
    float* out = (float*)d_out;

    char* wsb = (char*)d_ws;
    float*          qf32  = (float*)wsb;                         // [0, 32M)
    unsigned short* khi   = (unsigned short*)(wsb + (32u << 20));// [32M, 48M)
    unsigned short* klo   = khi + 8388608;                       // [48M, 64M)
    unsigned short* vthi  = (unsigned short*)(wsb + (64u << 20));// [64M, 80M)
    unsigned short* vtlo  = vthi + 8388608;                      // [80M, 96M)

    dim3 blk(256);
    const bool presplit = (ws_size >= 161480704ull);             // 154 MB

    if (presplit) {
        unsigned short* h1hi  = (unsigned short*)(wsb + (96u << 20));
        unsigned short* h1lo  = h1hi + 2097152;
        unsigned short* qhi   = (unsigned short*)(wsb + (104u << 20));
        unsigned short* qlo   = qhi + 8388608;
        unsigned short* wqhi  = (unsigned short*)(wsb + (136u << 20));
        unsigned short* wqlo  = wqhi + 1048576;
        unsigned short* wkhi  = wqlo + 1048576;
        unsigned short* wklo  = wkhi + 1048576;
        unsigned short* wvhi  = wklo + 1048576;
        unsigned short* wvlo  = wvhi + 1048576;
        unsigned short* wohi  = wvlo + 1048576;
        unsigned short* wolo  = wohi + 1048576;
        unsigned short* wm1hi = (unsigned short*)(wsb + (152u << 20));
        unsigned short* wm1lo = wm1hi + 262144;
        unsigned short* wm2hi = (unsigned short*)(wsb + (153u << 20));
        unsigned short* wm2lo = wm2hi + 262144;
        unsigned short* afhi  = khi;                             // attnf over k planes
        unsigned short* aflo  = klo;

        split_mat<<<8192, blk, 0, stream>>>(query, qhi, qlo, 2097152);
        split_mat<<<1024, blk, 0, stream>>>(Wq, wqhi, wqlo, 262144);
        split_mat<<<1024, blk, 0, stream>>>(Wk, wkhi, wklo, 262144);
        split_mat<<<1024, blk, 0, stream>>>(Wv, wvhi, wvlo, 262144);
        split_mat<<<1024, blk, 0, stream>>>(Wo, wohi, wolo, 262144);
        split_mat<<<256,  blk, 0, stream>>>(Wm1, wm1hi, wm1lo, 65536);
        split_mat<<<256,  blk, 0, stream>>>(Wm2, wm2hi, wm2lo, 65536);

        gemm_pl<1, false><<<dim3(PM / 128, PE / 128), blk, 0, stream>>>(
            qhi, qlo, wqhi, wqlo, bq, qf32, nullptr, nullptr, PM, PE, PE,
            nullptr, nullptr, nullptr, nullptr, nullptr, nullptr, nullptr);
        gemm_pl<3, false><<<dim3(PM / 128, PE / 128), blk, 0, stream>>>(
            qhi, qlo, wkhi, wklo, bk, nullptr, khi, klo, PM, PE, PE,
            nullptr, nullptr, nullptr, nullptr, nullptr, nullptr, nullptr);
        gemm_pl<4, false><<<dim3(PM / 128, PE / 128), blk, 0, stream>>>(
            qhi, qlo, wvhi, wvlo, bv, nullptr, vthi, vtlo, PM, PE, PE,
            nullptr, nullptr, nullptr, nullptr, nullptr, nullptr, nullptr);
        gemm_pl<5, true><<<dim3(PM / 128, 256 / 128), blk, 0, stream>>>(
            qhi, qlo, wm1hi, wm1lo, bm1, nullptr, h1hi, h1lo, PM, 256, PE,
            nullptr, nullptr, nullptr, nullptr, nullptr, nullptr, nullptr);

        flash_mfma<<<dim3(PS / 128, PH, PB), blk, 0, stream>>>(
            qf32, khi, klo, vthi, vtlo, qf32);

        gemm_pl<6, false><<<dim3(PM / 128, PE / 128), blk, 0, stream>>>(
            h1hi, h1lo, wm2hi, wm2lo, bm2, nullptr, afhi, aflo, PM, PE, 256,
            qf32, dop, ser, nor, ach, asc, abi);
        gemm_pl<0, false><<<dim3(PM / 128, PE / 128), blk, 0, stream>>>(
            afhi, aflo, wohi, wolo, bo, out, nullptr, nullptr, PM, PE, PE,
            nullptr, nullptr, nullptr, nullptr, nullptr, nullptr, nullptr);
    } else {
        float* h1    = (float*)(wsb + (96u << 20));
        float* attnf = (float*)khi;

        gemm_nt<1, false><<<dim3(PM / 128, PE / 128), blk, 0, stream>>>(
            query, Wq, bq, qf32, nullptr, nullptr, PM, PE, PE,
            nullptr, nullptr, nullptr, nullptr, nullptr, nullptr, nullptr);
        gemm_nt<3, false><<<dim3(PM / 128, PE / 128), blk, 0, stream>>>(
            query, Wk, bk, nullptr, khi, klo, PM, PE, PE,
            nullptr, nullptr, nullptr, nullptr, nullptr, nullptr, nullptr);
        gemm_nt<4, false><<<dim3(PM / 128, PE / 128), blk, 0, stream>>>(
            query, Wv, bv, nullptr, vthi, vtlo, PM, PE, PE,
            nullptr, nullptr, nullptr, nullptr, nullptr, nullptr, nullptr);
        gemm_nt<0, true><<<dim3(PM / 128, 256 / 128), blk, 0, stream>>>(
            query, Wm1, bm1, h1, nullptr, nullptr, PM, 256, PE,
            nullptr, nullptr, nullptr, nullptr, nullptr, nullptr, nullptr);

        flash_mfma<<<dim3(PS / 128, PH, PB), blk, 0, stream>>>(
            qf32, khi, klo, vthi, vtlo, qf32);

        gemm_nt<2, false><<<dim3(PM / 128, PE / 128), blk, 0, stream>>>(
            h1, Wm2, bm2, attnf, nullptr, nullptr, PM, PE, 256,
            qf32, dop, ser, nor, ach, asc, abi);
        gemm_nt<0, false><<<dim3(PM / 128, PE / 128), blk, 0, stream>>>(
            attnf, Wo, bo, out, nullptr, nullptr, PM, PE, PE,
            nullptr, nullptr, nullptr, nullptr, nullptr, nullptr, nullptr);
    }
}

// Round 8
// 442.659 us; speedup vs baseline: 1.2483x; 1.2483x over previous
//
#include <hip/hip_runtime.h>
#include <hip/hip_bf16.h>
#include <cstdint>

// Problem constants
#define PB 4
#define PS 2048
#define PE 1024
#define PH 16
#define PD 64
#define PM (PB * PS)      // 8192 rows

typedef __attribute__((ext_vector_type(8))) short short8;   // 8 bf16 (4 VGPR)
typedef __attribute__((ext_vector_type(4))) float f32x4;

#define MFMA16 __builtin_amdgcn_mfma_f32_16x16x32_bf16

#define GLOAD_LDS(gp, lp) __builtin_amdgcn_global_load_lds(                    \
    (const __attribute__((address_space(1))) void*)(gp),                       \
    (__attribute__((address_space(3))) void*)(lp), 16, 0, 0)

// fp32 -> bf16 round-to-nearest-even (finite inputs)
__device__ inline unsigned short bf16rn(float x) {
    unsigned u = __builtin_bit_cast(unsigned, x);
    u += 0x7FFFu + ((u >> 16) & 1u);
    return (unsigned short)(u >> 16);
}
__device__ inline float bf16tof(unsigned short h) {
    unsigned u = ((unsigned)h) << 16;
    return __builtin_bit_cast(float, u);
}
__device__ inline void split2(float x, unsigned short& h, unsigned short& l) {
    h = bf16rn(x);
    l = bf16rn(x - bf16tof(h));
}

// ---------------------------------------------------------------------------
// split_mat: fp32 matrix -> bf16 hi/lo planes (row-major, same shape)
// ---------------------------------------------------------------------------
__global__ __launch_bounds__(256)
void split_mat(const float* __restrict__ src, unsigned short* __restrict__ hi,
               unsigned short* __restrict__ lo, int n4)
{
    int i = blockIdx.x * 256 + threadIdx.x;
    if (i >= n4) return;
    float4 f = ((const float4*)src)[i];
    ushort4 h, l;
    split2(f.x, h.x, l.x); split2(f.y, h.y, l.y);
    split2(f.z, h.z, l.z); split2(f.w, h.w, l.w);
    ((ushort4*)hi)[i] = h;
    ((ushort4*)lo)[i] = l;
}

// ---------------------------------------------------------------------------
// Plane-fed split-bf16 MFMA NT GEMM (round-6 proven engine):
// A,B as bf16 hi/lo planes [rows][K]; staged via global_load_lds with
// pre-swizzled per-lane source (LDS = [128 rows][128B], byte^(row&7)<<4).
// BK=64, single buffer, ISSUE -> barrier -> 96 MFMA/wave -> barrier.
// Compensated product AhBh + AhBl + AlBh (~2^-17 rel).
// 128x128 tile, 4 waves (2x2) of 64x64; lane(lq,lg) owns
// C[16mt+4lg+j][16nt+lq] per 16x16 subtile.
// MODE 0: fp32 C[m*N+n]            (optional RELU)
// MODE 1: fp32 at BHSD index       (Q projection)
// MODE 3: bf16 hi/lo planes at BHSD index      (K projection)
// MODE 4: bf16 hi/lo planes at BHDS (V^T) index + PV seq permutation
// MODE 5: bf16 hi/lo planes row-major [M][N]   (h1, with RELU)
// MODE 6: neuromod combine -> bf16 hi/lo planes [M][N] (attnf)
// ---------------------------------------------------------------------------
template<int MODE, bool RELU>
__global__ __launch_bounds__(256, 2)
void gemm_pl(const unsigned short* __restrict__ Ahi,
             const unsigned short* __restrict__ Alo,
             const unsigned short* __restrict__ Bhi,
             const unsigned short* __restrict__ Blo,
             const float* __restrict__ bias, float* __restrict__ C,
             unsigned short* __restrict__ Ohi, unsigned short* __restrict__ Olo,
             int M, int N, int K,
             const float* __restrict__ attn,
             const float* __restrict__ g0, const float* __restrict__ g1,
             const float* __restrict__ g2, const float* __restrict__ g3,
             const float* __restrict__ asc, const float* __restrict__ abi)
{
    __shared__ int4 ldsq[4096];                 // 64 KB = 4 planes x 16 KB
    char* const lds = (char*)ldsq;

    const int tid  = threadIdx.x;
    const int lane = tid & 63;
    const int w    = tid >> 6;
    const int lq   = lane & 15;
    const int lg   = lane >> 4;
    const int wm   = (w >> 1) * 64;
    const int wn   = (w & 1) * 64;
    const int m0   = blockIdx.x * 128;
    const int n0   = blockIdx.y * 128;

    // staging source for this wave: 0:Ahi 1:Alo 2:Bhi 3:Blo
    const unsigned short* const gp =
        (w == 0) ? Ahi + (size_t)m0 * K :
        (w == 1) ? Alo + (size_t)m0 * K :
        (w == 2) ? Bhi + (size_t)n0 * K :
                   Blo + (size_t)n0 * K;
    const int ldsbase = w * 16384;
    const int scol8 = (((lane & 7) ^ (lane >> 3)) << 3);   // pre-swizzled col
    const int lrow8 = lane >> 3;

    f32x4 acc[4][4];
    #pragma unroll
    for (int mt = 0; mt < 4; ++mt)
        #pragma unroll
        for (int nt = 0; nt < 4; ++nt)
            acc[mt][nt] = (f32x4){0.f, 0.f, 0.f, 0.f};

    for (int k0 = 0; k0 < K; k0 += 64) {
        // ---- stage via global_load_lds (1 KB per wave-issue, 16 issues)
        #pragma unroll
        for (int r = 0; r < 16; ++r) {
            const int row = r * 8 + lrow8;
            GLOAD_LDS(gp + (size_t)row * K + k0 + scol8,
                      lds + ldsbase + r * 1024 + 16 * lane);
        }
        __syncthreads();

        // ---- compute: 96 MFMA per wave (3-term compensated)
        #pragma unroll
        for (int kh = 0; kh < 2; ++kh) {
            short8 afh[4], afl[4];
            #pragma unroll
            for (int mt = 0; mt < 4; ++mt) {
                const int row = wm + 16 * mt + lq;
                const int off = row * 128 + ((kh * 64 + 16 * lg) ^ ((row & 7) << 4));
                afh[mt] = *(const short8*)(lds + off);
                afl[mt] = *(const short8*)(lds + 16384 + off);
            }
            #pragma unroll
            for (int nt = 0; nt < 4; ++nt) {
                const int row = wn + 16 * nt + lq;
                const int off = row * 128 + ((kh * 64 + 16 * lg) ^ ((row & 7) << 4));
                short8 bfh = *(const short8*)(lds + 32768 + off);
                short8 bfl = *(const short8*)(lds + 49152 + off);
                #pragma unroll
                for (int mt = 0; mt < 4; ++mt) {
                    acc[mt][nt] = MFMA16(afh[mt], bfh, acc[mt][nt], 0, 0, 0);
                    acc[mt][nt] = MFMA16(afh[mt], bfl, acc[mt][nt], 0, 0, 0);
                    acc[mt][nt] = MFMA16(afl[mt], bfh, acc[mt][nt], 0, 0, 0);
                }
            }
        }
        __syncthreads();
    }

    float gain = 0.f, ascv = 0.f, abiv = 0.f;
    if (MODE == 6) {
        gain = 0.25f * (*g0 + *g1 + *g2 + *g3);
        ascv = *asc;
        abiv = *abi;
    }

    #pragma unroll
    for (int nt = 0; nt < 4; ++nt) {
        const int n  = n0 + wn + 16 * nt + lq;
        const float bv = bias[n];
        #pragma unroll
        for (int mt = 0; mt < 4; ++mt) {
            #pragma unroll
            for (int j = 0; j < 4; ++j) {
                const int m = m0 + wm + 16 * mt + 4 * lg + j;
                float v = acc[mt][nt][j] + bv;
                if (RELU) v = fmaxf(v, 0.f);
                if (MODE == 0) {
                    C[(size_t)m * N + n] = v;
                } else if (MODE == 1) {
                    const int b = m >> 11, s = m & 2047;
                    const int h = n >> 6, d = n & 63;
                    C[((size_t)(b * PH + h) * PS + s) * PD + d] = v;
                } else if (MODE == 3) {
                    const int b = m >> 11, s = m & 2047;
                    const int h = n >> 6, d = n & 63;
                    const size_t idx = ((size_t)(b * PH + h) * PS + s) * PD + d;
                    unsigned short hh, ll;
                    split2(v, hh, ll);
                    Ohi[idx] = hh; Olo[idx] = ll;
                } else if (MODE == 4) {
                    const int b = m >> 11;
                    const int h = n >> 6, d = n & 63;
                    const int scol = (m & 2047 & ~63) + ((mt & 1) << 5)
                                   + (lg << 3) + ((mt >> 1) << 2) + j;
                    const size_t idx = ((size_t)(b * PH + h) * PD + d) * PS + scol;
                    unsigned short hh, ll;
                    split2(v, hh, ll);
                    Ohi[idx] = hh; Olo[idx] = ll;
                } else if (MODE == 5) {
                    const size_t idx = (size_t)m * N + n;
                    unsigned short hh, ll;
                    split2(v, hh, ll);
                    Ohi[idx] = hh; Olo[idx] = ll;
                } else { // MODE 6
                    const int b = m >> 11, s = m & 2047;
                    const int h = n >> 6, d = n & 63;
                    const float av = attn[((size_t)(b * PH + h) * PS + s) * PD + d];
                    const float o = (av * ascv + abiv) * (1.f + v * gain);
                    const size_t idx = (size_t)m * N + n;
                    unsigned short hh, ll;
                    split2(o, hh, ll);
                    Ohi[idx] = hh; Olo[idx] = ll;
                }
            }
        }
    }
}

// ---------------------------------------------------------------------------
// fp32-fed split-bf16 MFMA NT GEMM (fallback path, round-5 proven).
// ---------------------------------------------------------------------------
template<int MODE, bool RELU>
__global__ __launch_bounds__(256, 2)
void gemm_nt(const float* __restrict__ A, const float* __restrict__ Bw,
             const float* __restrict__ bias, float* __restrict__ C,
             unsigned short* __restrict__ Ohi, unsigned short* __restrict__ Olo,
             int M, int N, int K,
             const float* __restrict__ attn,
             const float* __restrict__ g0, const float* __restrict__ g1,
             const float* __restrict__ g2, const float* __restrict__ g3,
             const float* __restrict__ asc, const float* __restrict__ abi)
{
    __shared__ int4 ldsq[4096];
    char* const lds = (char*)ldsq;

    const int tid  = threadIdx.x;
    const int lane = tid & 63;
    const int w    = tid >> 6;
    const int lq   = lane & 15;
    const int lg   = lane >> 4;
    const int wm   = (w >> 1) * 64;
    const int wn   = (w & 1) * 64;
    const int m0   = blockIdx.x * 128;
    const int n0   = blockIdx.y * 128;

    const int irow = tid >> 3;
    const int ic8  = (tid & 7) * 8;
    const int woff = (ic8 * 2);

    f32x4 acc[4][4];
    #pragma unroll
    for (int mt = 0; mt < 4; ++mt)
        #pragma unroll
        for (int nt = 0; nt < 4; ++nt)
            acc[mt][nt] = (f32x4){0.f, 0.f, 0.f, 0.f};

    for (int k0 = 0; k0 < K; k0 += 64) {
        #pragma unroll
        for (int mat = 0; mat < 2; ++mat) {
            const float* const src = mat ? Bw : A;
            const int rbase = mat ? n0 : m0;
            const int pbase = mat ? 32768 : 0;
            #pragma unroll
            for (int r = 0; r < 4; ++r) {
                const int row = irow + 32 * r;
                const float* p = src + (size_t)(rbase + row) * K + k0 + ic8;
                float4 f0 = *(const float4*)p;
                float4 f1 = *(const float4*)(p + 4);
                short8 vh, vl;
                {
                    unsigned short h, l;
                    split2(f0.x, h, l); vh[0] = (short)h; vl[0] = (short)l;
                    split2(f0.y, h, l); vh[1] = (short)h; vl[1] = (short)l;
                    split2(f0.z, h, l); vh[2] = (short)h; vl[2] = (short)l;
                    split2(f0.w, h, l); vh[3] = (short)h; vl[3] = (short)l;
                    split2(f1.x, h, l); vh[4] = (short)h; vl[4] = (short)l;
                    split2(f1.y, h, l); vh[5] = (short)h; vl[5] = (short)l;
                    split2(f1.z, h, l); vh[6] = (short)h; vl[6] = (short)l;
                    split2(f1.w, h, l); vh[7] = (short)h; vl[7] = (short)l;
                }
                const int off = row * 128 + (woff ^ ((row & 7) << 4));
                *(short8*)(lds + pbase + off)         = vh;
                *(short8*)(lds + pbase + 16384 + off) = vl;
            }
        }
        __syncthreads();

        #pragma unroll
        for (int kh = 0; kh < 2; ++kh) {
            short8 afh[4], afl[4];
            #pragma unroll
            for (int mt = 0; mt < 4; ++mt) {
                const int row = wm + 16 * mt + lq;
                const int off = row * 128 + ((kh * 64 + 16 * lg) ^ ((row & 7) << 4));
                afh[mt] = *(const short8*)(lds + off);
                afl[mt] = *(const short8*)(lds + 16384 + off);
            }
            #pragma unroll
            for (int nt = 0; nt < 4; ++nt) {
                const int row = wn + 16 * nt + lq;
                const int off = row * 128 + ((kh * 64 + 16 * lg) ^ ((row & 7) << 4));
                short8 bfh = *(const short8*)(lds + 32768 + off);
                short8 bfl = *(const short8*)(lds + 49152 + off);
                #pragma unroll
                for (int mt = 0; mt < 4; ++mt) {
                    acc[mt][nt] = MFMA16(afh[mt], bfh, acc[mt][nt], 0, 0, 0);
                    acc[mt][nt] = MFMA16(afh[mt], bfl, acc[mt][nt], 0, 0, 0);
                    acc[mt][nt] = MFMA16(afl[mt], bfh, acc[mt][nt], 0, 0, 0);
                }
            }
        }
        __syncthreads();
    }

    float gain = 0.f, ascv = 0.f, abiv = 0.f;
    if (MODE == 2) {
        gain = 0.25f * (*g0 + *g1 + *g2 + *g3);
        ascv = *asc;
        abiv = *abi;
    }

    #pragma unroll
    for (int nt = 0; nt < 4; ++nt) {
        const int n  = n0 + wn + 16 * nt + lq;
        const float bv = bias[n];
        #pragma unroll
        for (int mt = 0; mt < 4; ++mt) {
            #pragma unroll
            for (int j = 0; j < 4; ++j) {
                const int m = m0 + wm + 16 * mt + 4 * lg + j;
                float v = acc[mt][nt][j] + bv;
                if (RELU) v = fmaxf(v, 0.f);
                if (MODE == 0) {
                    C[(size_t)m * N + n] = v;
                } else if (MODE == 1) {
                    const int b = m >> 11, s = m & 2047;
                    const int h = n >> 6, d = n & 63;
                    C[((size_t)(b * PH + h) * PS + s) * PD + d] = v;
                } else if (MODE == 3) {
                    const int b = m >> 11, s = m & 2047;
                    const int h = n >> 6, d = n & 63;
                    const size_t idx = ((size_t)(b * PH + h) * PS + s) * PD + d;
                    unsigned short hh, ll;
                    split2(v, hh, ll);
                    Ohi[idx] = hh; Olo[idx] = ll;
                } else if (MODE == 4) {
                    const int b = m >> 11;
                    const int h = n >> 6, d = n & 63;
                    const int scol = (m & 2047 & ~63) + ((mt & 1) << 5)
                                   + (lg << 3) + ((mt >> 1) << 2) + j;
                    const size_t idx = ((size_t)(b * PH + h) * PD + d) * PS + scol;
                    unsigned short hh, ll;
                    split2(v, hh, ll);
                    Ohi[idx] = hh; Olo[idx] = ll;
                } else { // MODE 2
                    const int b = m >> 11, s = m & 2047;
                    const int h = n >> 6, d = n & 63;
                    const float av = attn[((size_t)(b * PH + h) * PS + s) * PD + d];
                    C[(size_t)m * N + n] = (av * ascv + abiv) * (1.f + v * gain);
                }
            }
        }
    }
}

// ---------------------------------------------------------------------------
// MFMA flash attention v5: v3 skeleton (64KB double-buffer, 2 blocks/CU,
// global_load_lds staging with pre-swizzled source) + P in single bf16
// (PV = Vhi.P + Vlo.P, 80 MFMA/tile) + defer-max (skip O-rescale unless
// pmax - m > 8; P bounded by e^8) + bijective XCD swizzle (1024 = 8x128:
// each XCD streams 8 bh sequentially -> K/V working set ~1MB < 4MB L2).
// ---------------------------------------------------------------------------
__global__ __launch_bounds__(256, 2)
void flash_mfma(const float* qf,
                const unsigned short* __restrict__ khi,
                const unsigned short* __restrict__ klo,
                const unsigned short* __restrict__ vthi,
                const unsigned short* __restrict__ vtlo,
                float* attn)
{
    __shared__ int4 ldsv[4096];                    // 64 KB: 2 bufs x 4 planes x 8KB
    char* const ldsb = (char*)ldsv;

    const int tid  = threadIdx.x;
    const int lane = tid & 63;
    const int w    = tid >> 6;
    const int lq   = lane & 15;
    const int lg   = lane >> 4;

    // XCD swizzle: phys linear -> logical so each XCD owns 128 consecutive
    // logical blocks (= 8 bh), streamed in order. Bijective: 1024 = 8*128.
    const int L  = blockIdx.x + (blockIdx.y << 4) + (blockIdx.z << 8);
    const int nL = ((L & 7) << 7) + (L >> 3);
    const int bh = nL >> 4;
    const int q0 = (nL & 15) * 128 + w * 32;

    const size_t kbase = (size_t)bh * PS * PD;   // K rows   [S][D]
    const size_t vbase = (size_t)bh * PD * PS;   // V^T rows [D][S] (permuted)

    const unsigned short* const gp =
        (w == 0) ? khi + kbase :
        (w == 1) ? klo + kbase :
        (w == 2) ? vthi + vbase :
                   vtlo + vbase;
    const bool isK = (w < 2);
    const int scol8 = (((lane & 7) ^ (lane >> 3)) << 3);   // pre-swizzled col
    const int lrow8 = lane >> 3;

    auto ISSUE = [&](int kt, int bufn) {
        #pragma unroll
        for (int r = 0; r < 8; ++r) {
            const int row = r * 8 + lrow8;
            const size_t goff = isK ? (size_t)(kt + row) * PD + scol8
                                    : (size_t)row * PS + kt + scol8;
            GLOAD_LDS(gp + goff,
                      ldsb + bufn * 32768 + w * 8192 + r * 1024 + 16 * lane);
        }
    };

    // ---- Q fragments (scale 1/8 folded in), 2 q-subtiles per wave
    short8 qh[2][2], ql[2][2];
    #pragma unroll
    for (int u = 0; u < 2; ++u) {
        const float* qp = qf + ((size_t)bh * PS + q0 + 16 * u + lq) * PD + 8 * lg;
        #pragma unroll
        for (int t = 0; t < 2; ++t)
            #pragma unroll
            for (int b = 0; b < 8; ++b) {
                float x = qp[t * 32 + b] * 0.125f;
                unsigned short h, l;
                split2(x, h, l);
                qh[u][t][b] = (short)h;
                ql[u][t][b] = (short)l;
            }
    }

    f32x4 ot[2][4];
    #pragma unroll
    for (int u = 0; u < 2; ++u)
        #pragma unroll
        for (int mt = 0; mt < 4; ++mt)
            ot[u][mt] = (f32x4){0.f, 0.f, 0.f, 0.f};
    float m_run[2] = {-3.0e38f, -3.0e38f};
    float l_run[2] = {0.f, 0.f};

    ISSUE(0, 0);
    __syncthreads();

    int buf = 0;
    for (int kti = 0; kti < PS / 64; ++kti) {
        const bool pf = (kti + 1 < PS / 64);
        if (pf) ISSUE((kti + 1) * 64, buf ^ 1);

        const char* const L2 = ldsb + buf * 32768;

        // ---- S^T tiles for both q-subtiles (3-term compensated)
        f32x4 st[2][4];
        #pragma unroll
        for (int mt = 0; mt < 4; ++mt) {
            const int row = 16 * mt + lq;
            const int swz = (row & 7) << 4;
            const char* kr = L2 + row * 128;
            short8 ah0 = *(const short8*)(kr + ((16 * lg) ^ swz));
            short8 ah1 = *(const short8*)(kr + ((64 + 16 * lg) ^ swz));
            short8 al0 = *(const short8*)(kr + 8192 + ((16 * lg) ^ swz));
            short8 al1 = *(const short8*)(kr + 8192 + ((64 + 16 * lg) ^ swz));
            #pragma unroll
            for (int u = 0; u < 2; ++u) {
                f32x4 acc = {0.f, 0.f, 0.f, 0.f};
                acc = MFMA16(ah0, qh[u][0], acc, 0, 0, 0);
                acc = MFMA16(ah1, qh[u][1], acc, 0, 0, 0);
                acc = MFMA16(ah0, ql[u][0], acc, 0, 0, 0);
                acc = MFMA16(ah1, ql[u][1], acc, 0, 0, 0);
                acc = MFMA16(al0, qh[u][0], acc, 0, 0, 0);
                acc = MFMA16(al1, qh[u][1], acc, 0, 0, 0);
                st[u][mt] = acc;
            }
        }

        // ---- online softmax (defer-max) + P pack (single bf16)
        short8 pb[2][2];
        #pragma unroll
        for (int u = 0; u < 2; ++u) {
            float pmax = -3.0e38f;
            #pragma unroll
            for (int mt = 0; mt < 4; ++mt)
                #pragma unroll
                for (int j = 0; j < 4; ++j)
                    pmax = fmaxf(pmax, st[u][mt][j]);
            pmax = fmaxf(pmax, __shfl_xor(pmax, 16));
            pmax = fmaxf(pmax, __shfl_xor(pmax, 32));
            if (!__all(pmax - m_run[u] <= 8.f)) {   // rare: rescale path
                float mnew = fmaxf(m_run[u], pmax);
                float corr = __expf(m_run[u] - mnew);
                l_run[u] *= corr;
                m_run[u] = mnew;
                #pragma unroll
                for (int mt = 0; mt < 4; ++mt)
                    #pragma unroll
                    for (int j = 0; j < 4; ++j)
                        ot[u][mt][j] *= corr;
            }
            float psum = 0.f;
            #pragma unroll
            for (int mt = 0; mt < 4; ++mt)
                #pragma unroll
                for (int j = 0; j < 4; ++j) {
                    float p = __expf(st[u][mt][j] - m_run[u]);
                    psum += p;
                    st[u][mt][j] = p;
                }
            psum += __shfl_xor(psum, 16);
            psum += __shfl_xor(psum, 32);
            l_run[u] += psum;
            #pragma unroll
            for (int b = 0; b < 8; ++b) {
                const int mt0 = (b >> 2) << 1;
                pb[u][0][b] = (short)bf16rn(st[u][mt0][b & 3]);
                pb[u][1][b] = (short)bf16rn(st[u][mt0 + 1][b & 3]);
            }
        }

        // ---- O^T += V^T . P^T   (V hi/lo, P single: 2 MFMA each)
        #pragma unroll
        for (int t = 0; t < 2; ++t) {
            #pragma unroll
            for (int mt = 0; mt < 4; ++mt) {
                const int row = 16 * mt + lq;
                const int swz = (row & 7) << 4;
                const char* vr = L2 + 16384 + row * 128;
                short8 vh = *(const short8*)(vr + ((t * 64 + 16 * lg) ^ swz));
                short8 vl = *(const short8*)(vr + 8192 + ((t * 64 + 16 * lg) ^ swz));
                #pragma unroll
                for (int u = 0; u < 2; ++u) {
                    ot[u][mt] = MFMA16(vh, pb[u][t], ot[u][mt], 0, 0, 0);
                    ot[u][mt] = MFMA16(vl, pb[u][t], ot[u][mt], 0, 0, 0);
                }
            }
        }

        __syncthreads();        // drains prefetch vmcnt + protects LDS reuse
        buf ^= 1;
    }

    // ---- epilogue: attn[bh][q0+16u+lq][d], d = 16*mt + 4*lg + j
    #pragma unroll
    for (int u = 0; u < 2; ++u) {
        const float inv = 1.f / l_run[u];
        float* op = attn + ((size_t)bh * PS + q0 + 16 * u + lq) * PD + 4 * lg;
        #pragma unroll
        for (int mt = 0; mt < 4; ++mt) {
            float4 o;
            o.x = ot[u][mt][0] * inv; o.y = ot[u][mt][1] * inv;
            o.z = ot[u][mt][2] * inv; o.w = ot[u][mt][3] * inv;
            *(float4*)(op + 16 * mt) = o;
        }
    }
}

// ---------------------------------------------------------------------------
extern "C" void kernel_launch(void* const* d_in, const int* in_sizes, int n_in,
                              void* d_out, int out_size, void* d_ws, size_t ws_size,
                              hipStream_t stream)
{
    const float* query = (const float*)d_in[0];
    const float* Wq  = (const float*)d_in[1];  const float* bq  = (const float*)d_in[2];
    const float* Wk  = (const float*)d_in[3];  const float* bk  = (const float*)d_in[4];
    const float* Wv  = (const float*)d_in[5];  const float* bv  = (const float*)d_in[6];
    const float* Wo  = (const float*)d_in[7];  const float* bo  = (const float*)d_in[8];
    const float* Wm1 = (const float*)d_in[9];  const float* bm1 = (const float*)d_in[10];
    const float* Wm2 = (const float*)d_in[11]; const float* bm2 = (const float*)d_in[12];
    const float* dop = (const float*)d_in[13];
    const float* ser = (const float*)d_in[14];
    const float* nor = (const float*)d_in[15];
    const float* ach = (const float*)d_in[16];
    const float* asc = (const float*)d_in[17];
    const float* abi = (const float*)d_in[18];
    float* out = (float*)d_out;

    char* wsb = (char*)d_ws;
    float*          qf32  = (float*)wsb;                         // [0, 32M)
    unsigned short* khi   = (unsigned short*)(wsb + (32u << 20));// [32M, 48M)
    unsigned short* klo   = khi + 8388608;                       // [48M, 64M)
    unsigned short* vthi  = (unsigned short*)(wsb + (64u << 20));// [64M, 80M)
    unsigned short* vtlo  = vthi + 8388608;                      // [80M, 96M)

    dim3 blk(256);
    const bool presplit = (ws_size >= 161480704ull);             // 154 MB

    if (presplit) {
        unsigned short* h1hi  = (unsigned short*)(wsb + (96u << 20));
        unsigned short* h1lo  = h1hi + 2097152;
        unsigned short* qhi   = (unsigned short*)(wsb + (104u << 20));
        unsigned short* qlo   = qhi + 8388608;
        unsigned short* wqhi  = (unsigned short*)(wsb + (136u << 20));
        unsigned short* wqlo  = wqhi + 1048576;
        unsigned short* wkhi  = wqlo + 1048576;
        unsigned short* wklo  = wkhi + 1048576;
        unsigned short* wvhi  = wklo + 1048576;
        unsigned short* wvlo  = wvhi + 1048576;
        unsigned short* wohi  = wvlo + 1048576;
        unsigned short* wolo  = wohi + 1048576;
        unsigned short* wm1hi = (unsigned short*)(wsb + (152u << 20));
        unsigned short* wm1lo = wm1hi + 262144;
        unsigned short* wm2hi = (unsigned short*)(wsb + (153u << 20));
        unsigned short* wm2lo = wm2hi + 262144;
        unsigned short* afhi  = khi;                             // attnf over k planes
        unsigned short* aflo  = klo;

        split_mat<<<8192, blk, 0, stream>>>(query, qhi, qlo, 2097152);
        split_mat<<<1024, blk, 0, stream>>>(Wq, wqhi, wqlo, 262144);
        split_mat<<<1024, blk, 0, stream>>>(Wk, wkhi, wklo, 262144);
        split_mat<<<1024, blk, 0, stream>>>(Wv, wvhi, wvlo, 262144);
        split_mat<<<1024, blk, 0, stream>>>(Wo, wohi, wolo, 262144);
        split_mat<<<256,  blk, 0, stream>>>(Wm1, wm1hi, wm1lo, 65536);
        split_mat<<<256,  blk, 0, stream>>>(Wm2, wm2hi, wm2lo, 65536);

        gemm_pl<1, false><<<dim3(PM / 128, PE / 128), blk, 0, stream>>>(
            qhi, qlo, wqhi, wqlo, bq, qf32, nullptr, nullptr, PM, PE, PE,
            nullptr, nullptr, nullptr, nullptr, nullptr, nullptr, nullptr);
        gemm_pl<3, false><<<dim3(PM / 128, PE / 128), blk, 0, stream>>>(
            qhi, qlo, wkhi, wklo, bk, nullptr, khi, klo, PM, PE, PE,
            nullptr, nullptr, nullptr, nullptr, nullptr, nullptr, nullptr);
        gemm_pl<4, false><<<dim3(PM / 128, PE / 128), blk, 0, stream>>>(
            qhi, qlo, wvhi, wvlo, bv, nullptr, vthi, vtlo, PM, PE, PE,
            nullptr, nullptr, nullptr, nullptr, nullptr, nullptr, nullptr);
        gemm_pl<5, true><<<dim3(PM / 128, 256 / 128), blk, 0, stream>>>(
            qhi, qlo, wm1hi, wm1lo, bm1, nullptr, h1hi, h1lo, PM, 256, PE,
            nullptr, nullptr, nullptr, nullptr, nullptr, nullptr, nullptr);

        flash_mfma<<<dim3(PS / 128, PH, PB), blk, 0, stream>>>(
            qf32, khi, klo, vthi, vtlo, qf32);

        gemm_pl<6, false><<<dim3(PM / 128, PE / 128), blk, 0, stream>>>(
            h1hi, h1lo, wm2hi, wm2lo, bm2, nullptr, afhi, aflo, PM, PE, 256,
            qf32, dop, ser, nor, ach, asc, abi);
        gemm_pl<0, false><<<dim3(PM / 128, PE / 128), blk, 0, stream>>>(
            afhi, aflo, wohi, wolo, bo, out, nullptr, nullptr, PM, PE, PE,
            nullptr, nullptr, nullptr, nullptr, nullptr, nullptr, nullptr);
    } else {
        float* h1    = (float*)(wsb + (96u << 20));
        float* attnf = (float*)khi;

        gemm_nt<1, false><<<dim3(PM / 128, PE / 128), blk, 0, stream>>>(
            query, Wq, bq, qf32, nullptr, nullptr, PM, PE, PE,
            nullptr, nullptr, nullptr, nullptr, nullptr, nullptr, nullptr);
        gemm_nt<3, false><<<dim3(PM / 128, PE / 128), blk, 0, stream>>>(
            query, Wk, bk, nullptr, khi, klo, PM, PE, PE,
            nullptr, nullptr, nullptr, nullptr, nullptr, nullptr, nullptr);
        gemm_nt<4, false><<<dim3(PM / 128, PE / 128), blk, 0, stream>>>(
            query, Wv, bv, nullptr, vthi, vtlo, PM, PE, PE,
            nullptr, nullptr, nullptr, nullptr, nullptr, nullptr, nullptr);
        gemm_nt<0, true><<<dim3(PM / 128, 256 / 128), blk, 0, stream>>>(
            query, Wm1, bm1, h1, nullptr, nullptr, PM, 256, PE,
            nullptr, nullptr, nullptr, nullptr, nullptr, nullptr, nullptr);

        flash_mfma<<<dim3(PS / 128, PH, PB), blk, 0, stream>>>(
            qf32, khi, klo, vthi, vtlo, qf32);

        gemm_nt<2, false><<<dim3(PM / 128, PE / 128), blk, 0, stream>>>(
            h1, Wm2, bm2, attnf, nullptr, nullptr, PM, PE, 256,
            qf32, dop, ser, nor, ach, asc, abi);
        gemm_nt<0, false><<<dim3(PM / 128, PE / 128), blk, 0, stream>>>(
            attnf, Wo, bo, out, nullptr, nullptr, PM, PE, PE,
            nullptr, nullptr, nullptr, nullptr, nullptr, nullptr, nullptr);
    }
}

// Round 10
// 424.656 us; speedup vs baseline: 1.3013x; 1.0424x over previous
//
#include <hip/hip_runtime.h>
#include <hip/hip_bf16.h>
#include <cstdint>

// Problem constants
#define PB 4
#define PS 2048
#define PE 1024
#define PH 16
#define PD 64
#define PM (PB * PS)      // 8192 rows

typedef __attribute__((ext_vector_type(8))) short short8;   // 8 bf16 (4 VGPR)
typedef __attribute__((ext_vector_type(4))) float f32x4;

#define MFMA16 __builtin_amdgcn_mfma_f32_16x16x32_bf16

#define GLOAD_LDS(gp, lp) __builtin_amdgcn_global_load_lds(                    \
    (const __attribute__((address_space(1))) void*)(gp),                       \
    (__attribute__((address_space(3))) void*)(lp), 16, 0, 0)

// fp32 -> bf16 round-to-nearest-even (finite inputs)
__device__ inline unsigned short bf16rn(float x) {
    unsigned u = __builtin_bit_cast(unsigned, x);
    u += 0x7FFFu + ((u >> 16) & 1u);
    return (unsigned short)(u >> 16);
}
__device__ inline float bf16tof(unsigned short h) {
    unsigned u = ((unsigned)h) << 16;
    return __builtin_bit_cast(float, u);
}
__device__ inline void split2(float x, unsigned short& h, unsigned short& l) {
    h = bf16rn(x);
    l = bf16rn(x - bf16tof(h));
}
// packed pair: low16 = bf16(a), high16 = bf16(b)  (v_cvt_pk_bf16_f32 path)
__device__ inline unsigned pk2(float a, float b) {
    __hip_bfloat162 t = __float22bfloat162_rn(make_float2(a, b));
    unsigned u;
    __builtin_memcpy(&u, &t, 4);
    return u;
}

// ---------------------------------------------------------------------------
// split_all: all 7 fp32 operands -> bf16 hi/lo planes in ONE launch.
// f4 ranges: query 2097152 | Wq/Wk/Wv/Wo 262144 each | Wm1/Wm2 65536 each.
// ---------------------------------------------------------------------------
__global__ __launch_bounds__(256)
void split_all(const float* __restrict__ q,   const float* __restrict__ wq,
               const float* __restrict__ wk,  const float* __restrict__ wv,
               const float* __restrict__ wo,  const float* __restrict__ wm1,
               const float* __restrict__ wm2,
               unsigned short* qhi,  unsigned short* qlo,
               unsigned short* wqhi, unsigned short* wqlo,
               unsigned short* wkhi, unsigned short* wklo,
               unsigned short* wvhi, unsigned short* wvlo,
               unsigned short* wohi, unsigned short* wolo,
               unsigned short* m1hi, unsigned short* m1lo,
               unsigned short* m2hi, unsigned short* m2lo)
{
    const int b = blockIdx.x;
    const float* src; unsigned short *hi, *lo; int base;
    if      (b <  8192) { src = q;   hi = qhi;  lo = qlo;  base = 0;     }
    else if (b <  9216) { src = wq;  hi = wqhi; lo = wqlo; base = 8192;  }
    else if (b < 10240) { src = wk;  hi = wkhi; lo = wklo; base = 9216;  }
    else if (b < 11264) { src = wv;  hi = wvhi; lo = wvlo; base = 10240; }
    else if (b < 12288) { src = wo;  hi = wohi; lo = wolo; base = 11264; }
    else if (b < 12544) { src = wm1; hi = m1hi; lo = m1lo; base = 12288; }
    else                { src = wm2; hi = m2hi; lo = m2lo; base = 12544; }
    const int i = (b - base) * 256 + threadIdx.x;
    float4 f = ((const float4*)src)[i];
    ushort4 h, l;
    split2(f.x, h.x, l.x); split2(f.y, h.y, l.y);
    split2(f.z, h.z, l.z); split2(f.w, h.w, l.w);
    ((ushort4*)hi)[i] = h;
    ((ushort4*)lo)[i] = l;
}

// ---------------------------------------------------------------------------
// Plane-fed split-bf16 MFMA NT GEMM (round-6 proven engine, unchanged).
// ---------------------------------------------------------------------------
template<int MODE, bool RELU>
__global__ __launch_bounds__(256, 2)
void gemm_pl(const unsigned short* __restrict__ Ahi,
             const unsigned short* __restrict__ Alo,
             const unsigned short* __restrict__ Bhi,
             const unsigned short* __restrict__ Blo,
             const float* __restrict__ bias, float* __restrict__ C,
             unsigned short* __restrict__ Ohi, unsigned short* __restrict__ Olo,
             int M, int N, int K,
             const float* __restrict__ attn,
             const float* __restrict__ g0, const float* __restrict__ g1,
             const float* __restrict__ g2, const float* __restrict__ g3,
             const float* __restrict__ asc, const float* __restrict__ abi)
{
    __shared__ int4 ldsq[4096];                 // 64 KB = 4 planes x 16 KB
    char* const lds = (char*)ldsq;

    const int tid  = threadIdx.x;
    const int lane = tid & 63;
    const int w    = tid >> 6;
    const int lq   = lane & 15;
    const int lg   = lane >> 4;
    const int wm   = (w >> 1) * 64;
    const int wn   = (w & 1) * 64;
    const int m0   = blockIdx.x * 128;
    const int n0   = blockIdx.y * 128;

    const unsigned short* const gp =
        (w == 0) ? Ahi + (size_t)m0 * K :
        (w == 1) ? Alo + (size_t)m0 * K :
        (w == 2) ? Bhi + (size_t)n0 * K :
                   Blo + (size_t)n0 * K;
    const int ldsbase = w * 16384;
    const int scol8 = (((lane & 7) ^ (lane >> 3)) << 3);   // pre-swizzled col
    const int lrow8 = lane >> 3;

    f32x4 acc[4][4];
    #pragma unroll
    for (int mt = 0; mt < 4; ++mt)
        #pragma unroll
        for (int nt = 0; nt < 4; ++nt)
            acc[mt][nt] = (f32x4){0.f, 0.f, 0.f, 0.f};

    for (int k0 = 0; k0 < K; k0 += 64) {
        #pragma unroll
        for (int r = 0; r < 16; ++r) {
            const int row = r * 8 + lrow8;
            GLOAD_LDS(gp + (size_t)row * K + k0 + scol8,
                      lds + ldsbase + r * 1024 + 16 * lane);
        }
        __syncthreads();

        #pragma unroll
        for (int kh = 0; kh < 2; ++kh) {
            short8 afh[4], afl[4];
            #pragma unroll
            for (int mt = 0; mt < 4; ++mt) {
                const int row = wm + 16 * mt + lq;
                const int off = row * 128 + ((kh * 64 + 16 * lg) ^ ((row & 7) << 4));
                afh[mt] = *(const short8*)(lds + off);
                afl[mt] = *(const short8*)(lds + 16384 + off);
            }
            #pragma unroll
            for (int nt = 0; nt < 4; ++nt) {
                const int row = wn + 16 * nt + lq;
                const int off = row * 128 + ((kh * 64 + 16 * lg) ^ ((row & 7) << 4));
                short8 bfh = *(const short8*)(lds + 32768 + off);
                short8 bfl = *(const short8*)(lds + 49152 + off);
                #pragma unroll
                for (int mt = 0; mt < 4; ++mt) {
                    acc[mt][nt] = MFMA16(afh[mt], bfh, acc[mt][nt], 0, 0, 0);
                    acc[mt][nt] = MFMA16(afh[mt], bfl, acc[mt][nt], 0, 0, 0);
                    acc[mt][nt] = MFMA16(afl[mt], bfh, acc[mt][nt], 0, 0, 0);
                }
            }
        }
        __syncthreads();
    }

    float gain = 0.f, ascv = 0.f, abiv = 0.f;
    if (MODE == 6) {
        gain = 0.25f * (*g0 + *g1 + *g2 + *g3);
        ascv = *asc;
        abiv = *abi;
    }

    #pragma unroll
    for (int nt = 0; nt < 4; ++nt) {
        const int n  = n0 + wn + 16 * nt + lq;
        const float bv = bias[n];
        #pragma unroll
        for (int mt = 0; mt < 4; ++mt) {
            #pragma unroll
            for (int j = 0; j < 4; ++j) {
                const int m = m0 + wm + 16 * mt + 4 * lg + j;
                float v = acc[mt][nt][j] + bv;
                if (RELU) v = fmaxf(v, 0.f);
                if (MODE == 0) {
                    C[(size_t)m * N + n] = v;
                } else if (MODE == 1) {
                    const int b = m >> 11, s = m & 2047;
                    const int h = n >> 6, d = n & 63;
                    C[((size_t)(b * PH + h) * PS + s) * PD + d] = v;
                } else if (MODE == 3) {
                    const int b = m >> 11, s = m & 2047;
                    const int h = n >> 6, d = n & 63;
                    const size_t idx = ((size_t)(b * PH + h) * PS + s) * PD + d;
                    unsigned short hh, ll;
                    split2(v, hh, ll);
                    Ohi[idx] = hh; Olo[idx] = ll;
                } else if (MODE == 4) {
                    const int b = m >> 11;
                    const int h = n >> 6, d = n & 63;
                    const int scol = (m & 2047 & ~63) + ((mt & 1) << 5)
                                   + (lg << 3) + ((mt >> 1) << 2) + j;
                    const size_t idx = ((size_t)(b * PH + h) * PD + d) * PS + scol;
                    unsigned short hh, ll;
                    split2(v, hh, ll);
                    Ohi[idx] = hh; Olo[idx] = ll;
                } else if (MODE == 5) {
                    const size_t idx = (size_t)m * N + n;
                    unsigned short hh, ll;
                    split2(v, hh, ll);
                    Ohi[idx] = hh; Olo[idx] = ll;
                } else { // MODE 6
                    const int b = m >> 11, s = m & 2047;
                    const int h = n >> 6, d = n & 63;
                    const float av = attn[((size_t)(b * PH + h) * PS + s) * PD + d];
                    const float o = (av * ascv + abiv) * (1.f + v * gain);
                    const size_t idx = (size_t)m * N + n;
                    unsigned short hh, ll;
                    split2(o, hh, ll);
                    Ohi[idx] = hh; Olo[idx] = ll;
                }
            }
        }
    }
}

// ---------------------------------------------------------------------------
// fp32-fed split-bf16 MFMA NT GEMM (fallback path, round-5 proven).
// ---------------------------------------------------------------------------
template<int MODE, bool RELU>
__global__ __launch_bounds__(256, 2)
void gemm_nt(const float* __restrict__ A, const float* __restrict__ Bw,
             const float* __restrict__ bias, float* __restrict__ C,
             unsigned short* __restrict__ Ohi, unsigned short* __restrict__ Olo,
             int M, int N, int K,
             const float* __restrict__ attn,
             const float* __restrict__ g0, const float* __restrict__ g1,
             const float* __restrict__ g2, const float* __restrict__ g3,
             const float* __restrict__ asc, const float* __restrict__ abi)
{
    __shared__ int4 ldsq[4096];
    char* const lds = (char*)ldsq;

    const int tid  = threadIdx.x;
    const int lane = tid & 63;
    const int w    = tid >> 6;
    const int lq   = lane & 15;
    const int lg   = lane >> 4;
    const int wm   = (w >> 1) * 64;
    const int wn   = (w & 1) * 64;
    const int m0   = blockIdx.x * 128;
    const int n0   = blockIdx.y * 128;

    const int irow = tid >> 3;
    const int ic8  = (tid & 7) * 8;
    const int woff = (ic8 * 2);

    f32x4 acc[4][4];
    #pragma unroll
    for (int mt = 0; mt < 4; ++mt)
        #pragma unroll
        for (int nt = 0; nt < 4; ++nt)
            acc[mt][nt] = (f32x4){0.f, 0.f, 0.f, 0.f};

    for (int k0 = 0; k0 < K; k0 += 64) {
        #pragma unroll
        for (int mat = 0; mat < 2; ++mat) {
            const float* const src = mat ? Bw : A;
            const int rbase = mat ? n0 : m0;
            const int pbase = mat ? 32768 : 0;
            #pragma unroll
            for (int r = 0; r < 4; ++r) {
                const int row = irow + 32 * r;
                const float* p = src + (size_t)(rbase + row) * K + k0 + ic8;
                float4 f0 = *(const float4*)p;
                float4 f1 = *(const float4*)(p + 4);
                short8 vh, vl;
                {
                    unsigned short h, l;
                    split2(f0.x, h, l); vh[0] = (short)h; vl[0] = (short)l;
                    split2(f0.y, h, l); vh[1] = (short)h; vl[1] = (short)l;
                    split2(f0.z, h, l); vh[2] = (short)h; vl[2] = (short)l;
                    split2(f0.w, h, l); vh[3] = (short)h; vl[3] = (short)l;
                    split2(f1.x, h, l); vh[4] = (short)h; vl[4] = (short)l;
                    split2(f1.y, h, l); vh[5] = (short)h; vl[5] = (short)l;
                    split2(f1.z, h, l); vh[6] = (short)h; vl[6] = (short)l;
                    split2(f1.w, h, l); vh[7] = (short)h; vl[7] = (short)l;
                }
                const int off = row * 128 + (woff ^ ((row & 7) << 4));
                *(short8*)(lds + pbase + off)         = vh;
                *(short8*)(lds + pbase + 16384 + off) = vl;
            }
        }
        __syncthreads();

        #pragma unroll
        for (int kh = 0; kh < 2; ++kh) {
            short8 afh[4], afl[4];
            #pragma unroll
            for (int mt = 0; mt < 4; ++mt) {
                const int row = wm + 16 * mt + lq;
                const int off = row * 128 + ((kh * 64 + 16 * lg) ^ ((row & 7) << 4));
                afh[mt] = *(const short8*)(lds + off);
                afl[mt] = *(const short8*)(lds + 16384 + off);
            }
            #pragma unroll
            for (int nt = 0; nt < 4; ++nt) {
                const int row = wn + 16 * nt + lq;
                const int off = row * 128 + ((kh * 64 + 16 * lg) ^ ((row & 7) << 4));
                short8 bfh = *(const short8*)(lds + 32768 + off);
                short8 bfl = *(const short8*)(lds + 49152 + off);
                #pragma unroll
                for (int mt = 0; mt < 4; ++mt) {
                    acc[mt][nt] = MFMA16(afh[mt], bfh, acc[mt][nt], 0, 0, 0);
                    acc[mt][nt] = MFMA16(afh[mt], bfl, acc[mt][nt], 0, 0, 0);
                    acc[mt][nt] = MFMA16(afl[mt], bfh, acc[mt][nt], 0, 0, 0);
                }
            }
        }
        __syncthreads();
    }

    float gain = 0.f, ascv = 0.f, abiv = 0.f;
    if (MODE == 2) {
        gain = 0.25f * (*g0 + *g1 + *g2 + *g3);
        ascv = *asc;
        abiv = *abi;
    }

    #pragma unroll
    for (int nt = 0; nt < 4; ++nt) {
        const int n  = n0 + wn + 16 * nt + lq;
        const float bv = bias[n];
        #pragma unroll
        for (int mt = 0; mt < 4; ++mt) {
            #pragma unroll
            for (int j = 0; j < 4; ++j) {
                const int m = m0 + wm + 16 * mt + 4 * lg + j;
                float v = acc[mt][nt][j] + bv;
                if (RELU) v = fmaxf(v, 0.f);
                if (MODE == 0) {
                    C[(size_t)m * N + n] = v;
                } else if (MODE == 1) {
                    const int b = m >> 11, s = m & 2047;
                    const int h = n >> 6, d = n & 63;
                    C[((size_t)(b * PH + h) * PS + s) * PD + d] = v;
                } else if (MODE == 3) {
                    const int b = m >> 11, s = m & 2047;
                    const int h = n >> 6, d = n & 63;
                    const size_t idx = ((size_t)(b * PH + h) * PS + s) * PD + d;
                    unsigned short hh, ll;
                    split2(v, hh, ll);
                    Ohi[idx] = hh; Olo[idx] = ll;
                } else if (MODE == 4) {
                    const int b = m >> 11;
                    const int h = n >> 6, d = n & 63;
                    const int scol = (m & 2047 & ~63) + ((mt & 1) << 5)
                                   + (lg << 3) + ((mt >> 1) << 2) + j;
                    const size_t idx = ((size_t)(b * PH + h) * PD + d) * PS + scol;
                    unsigned short hh, ll;
                    split2(v, hh, ll);
                    Ohi[idx] = hh; Olo[idx] = ll;
                } else { // MODE 2
                    const int b = m >> 11, s = m & 2047;
                    const int h = n >> 6, d = n & 63;
                    const float av = attn[((size_t)(b * PH + h) * PS + s) * PD + d];
                    C[(size_t)m * N + n] = (av * ascv + abiv) * (1.f + v * gain);
                }
            }
        }
    }
}

// ---------------------------------------------------------------------------
// MFMA flash attention v6 = v5 (64KB dbuf, 2 blocks/CU, gload_lds staging,
// XCD swizzle, defer-max, single-bf16 P) with two issue-slot cuts:
//  - P pack via v_cvt_pk_bf16_f32 (__float22bfloat162_rn): 16 ops vs ~96
//  - l via MFMA(ones, P): column-sum of P lands in every lane's C regs
//    (col = lane&15 = this lane's q), replacing 32 adds + 4 shfl per tile.
// ---------------------------------------------------------------------------
__global__ __launch_bounds__(256, 2)
void flash_mfma(const float* qf,
                const unsigned short* __restrict__ khi,
                const unsigned short* __restrict__ klo,
                const unsigned short* __restrict__ vthi,
                const unsigned short* __restrict__ vtlo,
                float* attn)
{
    __shared__ int4 ldsv[4096];                    // 64 KB: 2 bufs x 4 planes x 8KB
    char* const ldsb = (char*)ldsv;

    const int tid  = threadIdx.x;
    const int lane = tid & 63;
    const int w    = tid >> 6;
    const int lq   = lane & 15;
    const int lg   = lane >> 4;

    // XCD swizzle: each XCD owns 128 consecutive logical blocks (= 8 bh).
    const int L  = blockIdx.x + (blockIdx.y << 4) + (blockIdx.z << 8);
    const int nL = ((L & 7) << 7) + (L >> 3);
    const int bh = nL >> 4;
    const int q0 = (nL & 15) * 128 + w * 32;

    const size_t kbase = (size_t)bh * PS * PD;   // K rows   [S][D]
    const size_t vbase = (size_t)bh * PD * PS;   // V^T rows [D][S] (permuted)

    const unsigned short* const gp =
        (w == 0) ? khi + kbase :
        (w == 1) ? klo + kbase :
        (w == 2) ? vthi + vbase :
                   vtlo + vbase;
    const bool isK = (w < 2);
    const int scol8 = (((lane & 7) ^ (lane >> 3)) << 3);   // pre-swizzled col
    const int lrow8 = lane >> 3;

    auto ISSUE = [&](int kt, int bufn) {
        #pragma unroll
        for (int r = 0; r < 8; ++r) {
            const int row = r * 8 + lrow8;
            const size_t goff = isK ? (size_t)(kt + row) * PD + scol8
                                    : (size_t)row * PS + kt + scol8;
            GLOAD_LDS(gp + goff,
                      ldsb + bufn * 32768 + w * 8192 + r * 1024 + 16 * lane);
        }
    };

    // all-ones bf16 A-fragment for the l-sum MFMA
    const short8 kones = {(short)0x3F80, (short)0x3F80, (short)0x3F80,
                          (short)0x3F80, (short)0x3F80, (short)0x3F80,
                          (short)0x3F80, (short)0x3F80};

    // ---- Q fragments (scale 1/8 folded in), 2 q-subtiles per wave
    short8 qh[2][2], ql[2][2];
    #pragma unroll
    for (int u = 0; u < 2; ++u) {
        const float* qp = qf + ((size_t)bh * PS + q0 + 16 * u + lq) * PD + 8 * lg;
        #pragma unroll
        for (int t = 0; t < 2; ++t)
            #pragma unroll
            for (int b = 0; b < 8; ++b) {
                float x = qp[t * 32 + b] * 0.125f;
                unsigned short h, l;
                split2(x, h, l);
                qh[u][t][b] = (short)h;
                ql[u][t][b] = (short)l;
            }
    }

    f32x4 ot[2][4];
    #pragma unroll
    for (int u = 0; u < 2; ++u)
        #pragma unroll
        for (int mt = 0; mt < 4; ++mt)
            ot[u][mt] = (f32x4){0.f, 0.f, 0.f, 0.f};
    f32x4 lacc[2] = {{0.f,0.f,0.f,0.f}, {0.f,0.f,0.f,0.f}};
    float m_run[2] = {-3.0e38f, -3.0e38f};

    ISSUE(0, 0);
    __syncthreads();

    int buf = 0;
    for (int kti = 0; kti < PS / 64; ++kti) {
        const bool pf = (kti + 1 < PS / 64);
        if (pf) ISSUE((kti + 1) * 64, buf ^ 1);

        const char* const L2 = ldsb + buf * 32768;

        // ---- S^T tiles for both q-subtiles (3-term compensated)
        f32x4 st[2][4];
        #pragma unroll
        for (int mt = 0; mt < 4; ++mt) {
            const int row = 16 * mt + lq;
            const int swz = (row & 7) << 4;
            const char* kr = L2 + row * 128;
            short8 ah0 = *(const short8*)(kr + ((16 * lg) ^ swz));
            short8 ah1 = *(const short8*)(kr + ((64 + 16 * lg) ^ swz));
            short8 al0 = *(const short8*)(kr + 8192 + ((16 * lg) ^ swz));
            short8 al1 = *(const short8*)(kr + 8192 + ((64 + 16 * lg) ^ swz));
            #pragma unroll
            for (int u = 0; u < 2; ++u) {
                f32x4 acc = {0.f, 0.f, 0.f, 0.f};
                acc = MFMA16(ah0, qh[u][0], acc, 0, 0, 0);
                acc = MFMA16(ah1, qh[u][1], acc, 0, 0, 0);
                acc = MFMA16(ah0, ql[u][0], acc, 0, 0, 0);
                acc = MFMA16(ah1, ql[u][1], acc, 0, 0, 0);
                acc = MFMA16(al0, qh[u][0], acc, 0, 0, 0);
                acc = MFMA16(al1, qh[u][1], acc, 0, 0, 0);
                st[u][mt] = acc;
            }
        }

        // ---- online softmax (defer-max) + P pack (cvt_pk) + l via MFMA
        short8 pb[2][2];
        #pragma unroll
        for (int u = 0; u < 2; ++u) {
            float pmax = -3.0e38f;
            #pragma unroll
            for (int mt = 0; mt < 4; ++mt)
                #pragma unroll
                for (int j = 0; j < 4; ++j)
                    pmax = fmaxf(pmax, st[u][mt][j]);
            pmax = fmaxf(pmax, __shfl_xor(pmax, 16));
            pmax = fmaxf(pmax, __shfl_xor(pmax, 32));
            if (!__all(pmax - m_run[u] <= 8.f)) {   // rare: rescale path
                float mnew = fmaxf(m_run[u], pmax);
                float corr = __expf(m_run[u] - mnew);
                m_run[u] = mnew;
                #pragma unroll
                for (int j = 0; j < 4; ++j)
                    lacc[u][j] *= corr;
                #pragma unroll
                for (int mt = 0; mt < 4; ++mt)
                    #pragma unroll
                    for (int j = 0; j < 4; ++j)
                        ot[u][mt][j] *= corr;
            }
            #pragma unroll
            for (int mt = 0; mt < 4; ++mt)
                #pragma unroll
                for (int j = 0; j < 4; ++j)
                    st[u][mt][j] = __expf(st[u][mt][j] - m_run[u]);
            // pb[u][t][b] = bf16(st[u][(b>>2)*2+t][b&3]); dword w of short8
            // holds elements (2w, 2w+1), low16 first.
            #pragma unroll
            for (int t = 0; t < 2; ++t) {
                unsigned w0 = pk2(st[u][t][0],     st[u][t][1]);
                unsigned w1 = pk2(st[u][t][2],     st[u][t][3]);
                unsigned w2 = pk2(st[u][t + 2][0], st[u][t + 2][1]);
                unsigned w3 = pk2(st[u][t + 2][2], st[u][t + 2][3]);
                uint4 pw = make_uint4(w0, w1, w2, w3);
                __builtin_memcpy(&pb[u][t], &pw, 16);
            }
            // l += colsum(P) for this lane's q column (all C rows identical)
            lacc[u] = MFMA16(kones, pb[u][0], lacc[u], 0, 0, 0);
            lacc[u] = MFMA16(kones, pb[u][1], lacc[u], 0, 0, 0);
        }

        // ---- O^T += V^T . P^T   (V hi/lo, P single: 2 MFMA each)
        #pragma unroll
        for (int t = 0; t < 2; ++t) {
            #pragma unroll
            for (int mt = 0; mt < 4; ++mt) {
                const int row = 16 * mt + lq;
                const int swz = (row & 7) << 4;
                const char* vr = L2 + 16384 + row * 128;
                short8 vh = *(const short8*)(vr + ((t * 64 + 16 * lg) ^ swz));
                short8 vl = *(const short8*)(vr + 8192 + ((t * 64 + 16 * lg) ^ swz));
                #pragma unroll
                for (int u = 0; u < 2; ++u) {
                    ot[u][mt] = MFMA16(vh, pb[u][t], ot[u][mt], 0, 0, 0);
                    ot[u][mt] = MFMA16(vl, pb[u][t], ot[u][mt], 0, 0, 0);
                }
            }
        }

        __syncthreads();        // drains prefetch vmcnt + protects LDS reuse
        buf ^= 1;
    }

    // ---- epilogue: attn[bh][q0+16u+lq][d], d = 16*mt + 4*lg + j
    #pragma unroll
    for (int u = 0; u < 2; ++u) {
        const float inv = 1.f / lacc[u][0];
        float* op = attn + ((size_t)bh * PS + q0 + 16 * u + lq) * PD + 4 * lg;
        #pragma unroll
        for (int mt = 0; mt < 4; ++mt) {
            float4 o;
            o.x = ot[u][mt][0] * inv; o.y = ot[u][mt][1] * inv;
            o.z = ot[u][mt][2] * inv; o.w = ot[u][mt][3] * inv;
            *(float4*)(op + 16 * mt) = o;
        }
    }
}

// ---------------------------------------------------------------------------
extern "C" void kernel_launch(void* const* d_in, const int* in_sizes, int n_in,
                              void* d_out, int out_size, void* d_ws, size_t ws_size,
                              hipStream_t stream)
{
    const float* query = (const float*)d_in[0];
    const float* Wq  = (const float*)d_in[1];  const float* bq  = (const float*)d_in[2];
    const float* Wk  = (const float*)d_in[3];  const float* bk  = (const float*)d_in[4];
    const float* Wv  = (const float*)d_in[5];  const float* bv  = (const float*)d_in[6];
    const float* Wo  = (const float*)d_in[7];  const float* bo  = (const float*)d_in[8];
    const float* Wm1 = (const float*)d_in[9];  const float* bm1 = (const float*)d_in[10];
    const float* Wm2 = (const float*)d_in[11]; const float* bm2 = (const float*)d_in[12];
    const float* dop = (const float*)d_in[13];
    const float* ser = (const float*)d_in[14];
    const float* nor = (const float*)d_in[15];
    const float* ach = (const float*)d_in[16];
    const float* asc = (const float*)d_in[17];
    const float* abi = (const float*)d_in[18];
    float* out = (float*)d_out;

    char* wsb = (char*)d_ws;
    float*          qf32  = (float*)wsb;                         // [0, 32M)
    unsigned short* khi   = (unsigned short*)(wsb + (32u << 20));// [32M, 48M)
    unsigned short* klo   = khi + 8388608;                       // [48M, 64M)
    unsigned short* vthi  = (unsigned short*)(wsb + (64u << 20));// [64M, 80M)
    unsigned short* vtlo  = vthi + 8388608;                      // [80M, 96M)

    dim3 blk(256);
    const bool presplit = (ws_size >= 161480704ull);             // 154 MB

    if (presplit) {
        unsigned short* h1hi  = (unsigned short*)(wsb + (96u << 20));
        unsigned short* h1lo  = h1hi + 2097152;
        unsigned short* qhi   = (unsigned short*)(wsb + (104u << 20));
        unsigned short* qlo   = qhi + 8388608;
        unsigned short* wqhi  = (unsigned short*)(wsb + (136u << 20));
        unsigned short* wqlo  = wqhi + 1048576;
        unsigned short* wkhi  = wqlo + 1048576;
        unsigned short* wklo  = wkhi + 1048576;
        unsigned short* wvhi  = wklo + 1048576;
        unsigned short* wvlo  = wvhi + 1048576;
        unsigned short* wohi  = wvlo + 1048576;
        unsigned short* wolo  = wohi + 1048576;
        unsigned short* wm1hi = (unsigned short*)(wsb + (152u << 20));
        unsigned short* wm1lo = wm1hi + 262144;
        unsigned short* wm2hi = (unsigned short*)(wsb + (153u << 20));
        unsigned short* wm2lo = wm2hi + 262144;
        unsigned short* afhi  = khi;                             // attnf over k planes
        unsigned short* aflo  = klo;

        split_all<<<12800, blk, 0, stream>>>(
            query, Wq, Wk, Wv, Wo, Wm1, Wm2,
            qhi, qlo, wqhi, wqlo, wkhi, wklo, wvhi, wvlo,
            wohi, wolo, wm1hi, wm1lo, wm2hi, wm2lo);

        gemm_pl<1, false><<<dim3(PM / 128, PE / 128), blk, 0, stream>>>(
            qhi, qlo, wqhi, wqlo, bq, qf32, nullptr, nullptr, PM, PE, PE,
            nullptr, nullptr, nullptr, nullptr, nullptr, nullptr, nullptr);
        gemm_pl<3, false><<<dim3(PM / 128, PE / 128), blk, 0, stream>>>(
            qhi, qlo, wkhi, wklo, bk, nullptr, khi, klo, PM, PE, PE,
            nullptr, nullptr, nullptr, nullptr, nullptr, nullptr, nullptr);
        gemm_pl<4, false><<<dim3(PM / 128, PE / 128), blk, 0, stream>>>(
            qhi, qlo, wvhi, wvlo, bv, nullptr, vthi, vtlo, PM, PE, PE,
            nullptr, nullptr, nullptr, nullptr, nullptr, nullptr, nullptr);
        gemm_pl<5, true><<<dim3(PM / 128, 256 / 128), blk, 0, stream>>>(
            qhi, qlo, wm1hi, wm1lo, bm1, nullptr, h1hi, h1lo, PM, 256, PE,
            nullptr, nullptr, nullptr, nullptr, nullptr, nullptr, nullptr);

        flash_mfma<<<dim3(PS / 128, PH, PB), blk, 0, stream>>>(
            qf32, khi, klo, vthi, vtlo, qf32);

        gemm_pl<6, false><<<dim3(PM / 128, PE / 128), blk, 0, stream>>>(
            h1hi, h1lo, wm2hi, wm2lo, bm2, nullptr, afhi, aflo, PM, PE, 256,
            qf32, dop, ser, nor, ach, asc, abi);
        gemm_pl<0, false><<<dim3(PM / 128, PE / 128), blk, 0, stream>>>(
            afhi, aflo, wohi, wolo, bo, out, nullptr, nullptr, PM, PE, PE,
            nullptr, nullptr, nullptr, nullptr, nullptr, nullptr, nullptr);
    } else {
        float* h1    = (float*)(wsb + (96u << 20));
        float* attnf = (float*)khi;

        gemm_nt<1, false><<<dim3(PM / 128, PE / 128), blk, 0, stream>>>(
            query, Wq, bq, qf32, nullptr, nullptr, PM, PE, PE,
            nullptr, nullptr, nullptr, nullptr, nullptr, nullptr, nullptr);
        gemm_nt<3, false><<<dim3(PM / 128, PE / 128), blk, 0, stream>>>(
            query, Wk, bk, nullptr, khi, klo, PM, PE, PE,
            nullptr, nullptr, nullptr, nullptr, nullptr, nullptr, nullptr);
        gemm_nt<4, false><<<dim3(PM / 128, PE / 128), blk, 0, stream>>>(
            query, Wv, bv, nullptr, vthi, vtlo, PM, PE, PE,
            nullptr, nullptr, nullptr, nullptr, nullptr, nullptr, nullptr);
        gemm_nt<0, true><<<dim3(PM / 128, 256 / 128), blk, 0, stream>>>(
            query, Wm1, bm1, h1, nullptr, nullptr, PM, 256, PE,
            nullptr, nullptr, nullptr, nullptr, nullptr, nullptr, nullptr);

        flash_mfma<<<dim3(PS / 128, PH, PB), blk, 0, stream>>>(
            qf32, khi, klo, vthi, vtlo, qf32);

        gemm_nt<2, false><<<dim3(PM / 128, PE / 128), blk, 0, stream>>>(
            h1, Wm2, bm2, attnf, nullptr, nullptr, PM, PE, 256,
            qf32, dop, ser, nor, ach, asc, abi);
        gemm_nt<0, false><<<dim3(PM / 128, PE / 128), blk, 0, stream>>>(
            attnf, Wo, bo, out, nullptr, nullptr, PM, PE, PE,
            nullptr, nullptr, nullptr, nullptr, nullptr, nullptr, nullptr);
    }
}

// Round 11
// 319.714 us; speedup vs baseline: 1.7284x; 1.3282x over previous
//
#include <hip/hip_runtime.h>
#include <hip/hip_bf16.h>
#include <cstdint>

// Problem constants
#define PB 4
#define PS 2048
#define PE 1024
#define PH 16
#define PD 64
#define PM (PB * PS)      // 8192 rows

typedef __attribute__((ext_vector_type(8))) _Float16 half8;  // 8 fp16 (4 VGPR)
typedef __attribute__((ext_vector_type(4))) float f32x4;

#define MFMAH __builtin_amdgcn_mfma_f32_16x16x32_f16

#define GLOAD_LDS(gp, lp) __builtin_amdgcn_global_load_lds(                    \
    (const __attribute__((address_space(1))) void*)(gp),                       \
    (__attribute__((address_space(3))) void*)(lp), 16, 0, 0)

// fp32 -> fp16 RNE bit pattern
__device__ inline unsigned short h16(float x) {
    _Float16 h = (_Float16)x;
    unsigned short u;
    __builtin_memcpy(&u, &h, 2);
    return u;
}
// fp16 hi/lo split (exact: x-hi is Sterbenz-exact in fp32)
__device__ inline void splith(float x, unsigned short& h, unsigned short& l) {
    _Float16 hh = (_Float16)x;
    _Float16 ll = (_Float16)(x - (float)hh);
    __builtin_memcpy(&h, &hh, 2);
    __builtin_memcpy(&l, &ll, 2);
}

// ---------------------------------------------------------------------------
// split_all: query -> fp16 hi/lo planes; weights -> single fp16 plane.
// f4 ranges: query 2097152 | Wq/Wk/Wv/Wo 262144 each | Wm1/Wm2 65536 each.
// ---------------------------------------------------------------------------
__global__ __launch_bounds__(256)
void split_all(const float* __restrict__ q,   const float* __restrict__ wq,
               const float* __restrict__ wk,  const float* __restrict__ wv,
               const float* __restrict__ wo,  const float* __restrict__ wm1,
               const float* __restrict__ wm2,
               unsigned short* qhi,  unsigned short* qlo,
               unsigned short* wqh, unsigned short* wkh,
               unsigned short* wvh, unsigned short* woh,
               unsigned short* m1h, unsigned short* m2h)
{
    const int b = blockIdx.x;
    if (b < 8192) {          // query: hi/lo
        const int i = b * 256 + threadIdx.x;
        float4 f = ((const float4*)q)[i];
        ushort4 h, l;
        splith(f.x, h.x, l.x); splith(f.y, h.y, l.y);
        splith(f.z, h.z, l.z); splith(f.w, h.w, l.w);
        ((ushort4*)qhi)[i] = h;
        ((ushort4*)qlo)[i] = l;
        return;
    }
    const float* src; unsigned short* dst; int base;
    if      (b <  9216) { src = wq;  dst = wqh; base = 8192;  }
    else if (b < 10240) { src = wk;  dst = wkh; base = 9216;  }
    else if (b < 11264) { src = wv;  dst = wvh; base = 10240; }
    else if (b < 12288) { src = wo;  dst = woh; base = 11264; }
    else if (b < 12544) { src = wm1; dst = m1h; base = 12288; }
    else                { src = wm2; dst = m2h; base = 12544; }
    const int i = (b - base) * 256 + threadIdx.x;
    float4 f = ((const float4*)src)[i];
    ushort4 h;
    h.x = h16(f.x); h.y = h16(f.y); h.z = h16(f.z); h.w = h16(f.w);
    ((ushort4*)dst)[i] = h;
}

// ---------------------------------------------------------------------------
// Plane-fed 2-term fp16 MFMA NT GEMM:
// A as fp16 hi/lo planes [rows][K]; B (weights) single fp16 plane.
// Product = AhB + AlB (error = A*epsB ~ 2^-11 rel). BK=64, single buffer,
// LDS = 3 planes x 16KB (Ahi, Alo, B), XOR swizzle byte^(row&7)<<4,
// staged via global_load_lds with pre-swizzled source.
// 128x128 tile, 4 waves (2x2) of 64x64; lane(lq,lg) owns
// C[16mt+4lg+j][16nt+lq] per 16x16 subtile. 64 MFMA/wave/step.
// MODE 0: fp32 C[m*N+n]            (optional RELU)
// MODE 1: fp32 at BHSD index       (Q projection)
// MODE 3: fp16 single at BHSD index        (K projection)
// MODE 4: fp16 single at BHDS + PV seq permutation (V^T)
// MODE 5: fp16 hi/lo planes row-major [M][N]   (h1, with RELU)
// MODE 6: neuromod combine -> fp16 hi/lo planes [M][N] (attnf)
// ---------------------------------------------------------------------------
template<int MODE, bool RELU>
__global__ __launch_bounds__(256, 2)
void gemm_pl(const unsigned short* __restrict__ Ahi,
             const unsigned short* __restrict__ Alo,
             const unsigned short* __restrict__ Bh,
             const float* __restrict__ bias, float* __restrict__ C,
             unsigned short* __restrict__ Ohi, unsigned short* __restrict__ Olo,
             int M, int N, int K,
             const float* __restrict__ attn,
             const float* __restrict__ g0, const float* __restrict__ g1,
             const float* __restrict__ g2, const float* __restrict__ g3,
             const float* __restrict__ asc, const float* __restrict__ abi)
{
    __shared__ int4 ldsq[3072];                 // 48 KB = 3 planes x 16 KB
    char* const lds = (char*)ldsq;

    const int tid  = threadIdx.x;
    const int lane = tid & 63;
    const int w    = tid >> 6;
    const int lq   = lane & 15;
    const int lg   = lane >> 4;
    const int wm   = (w >> 1) * 64;
    const int wn   = (w & 1) * 64;
    const int m0   = blockIdx.x * 128;
    const int n0   = blockIdx.y * 128;

    // staging roles: w0: Ahi c0-15 | w1: Alo c0-15 | w2: B c0-7 | w3: B c8-15
    const unsigned short* const gp =
        (w == 0) ? Ahi + (size_t)m0 * K :
        (w == 1) ? Alo + (size_t)m0 * K :
                   Bh  + (size_t)n0 * K;
    const int pbase = (w == 0) ? 0 : (w == 1) ? 16384 : 32768;
    const int c0    = (w == 3) ? 8 : 0;
    const int cnt   = (w < 2) ? 16 : 8;
    const int scol8 = (((lane & 7) ^ (lane >> 3)) << 3);   // pre-swizzled col
    const int lrow8 = lane >> 3;

    f32x4 acc[4][4];
    #pragma unroll
    for (int mt = 0; mt < 4; ++mt)
        #pragma unroll
        for (int nt = 0; nt < 4; ++nt)
            acc[mt][nt] = (f32x4){0.f, 0.f, 0.f, 0.f};

    for (int k0 = 0; k0 < K; k0 += 64) {
        #pragma unroll
        for (int r = 0; r < 16; ++r) {
            if (r < cnt) {
                const int c = c0 + r;
                GLOAD_LDS(gp + (size_t)(c * 8 + lrow8) * K + k0 + scol8,
                          lds + pbase + c * 1024 + 16 * lane);
            }
        }
        __syncthreads();

        #pragma unroll
        for (int kh = 0; kh < 2; ++kh) {
            half8 afh[4], afl[4];
            #pragma unroll
            for (int mt = 0; mt < 4; ++mt) {
                const int row = wm + 16 * mt + lq;
                const int off = row * 128 + ((kh * 64 + 16 * lg) ^ ((row & 7) << 4));
                afh[mt] = *(const half8*)(lds + off);
                afl[mt] = *(const half8*)(lds + 16384 + off);
            }
            #pragma unroll
            for (int nt = 0; nt < 4; ++nt) {
                const int row = wn + 16 * nt + lq;
                const int off = row * 128 + ((kh * 64 + 16 * lg) ^ ((row & 7) << 4));
                half8 bf = *(const half8*)(lds + 32768 + off);
                #pragma unroll
                for (int mt = 0; mt < 4; ++mt) {
                    acc[mt][nt] = MFMAH(afh[mt], bf, acc[mt][nt], 0, 0, 0);
                    acc[mt][nt] = MFMAH(afl[mt], bf, acc[mt][nt], 0, 0, 0);
                }
            }
        }
        __syncthreads();
    }

    float gain = 0.f, ascv = 0.f, abiv = 0.f;
    if (MODE == 6) {
        gain = 0.25f * (*g0 + *g1 + *g2 + *g3);
        ascv = *asc;
        abiv = *abi;
    }

    #pragma unroll
    for (int nt = 0; nt < 4; ++nt) {
        const int n  = n0 + wn + 16 * nt + lq;
        const float bv = bias[n];
        #pragma unroll
        for (int mt = 0; mt < 4; ++mt) {
            #pragma unroll
            for (int j = 0; j < 4; ++j) {
                const int m = m0 + wm + 16 * mt + 4 * lg + j;
                float v = acc[mt][nt][j] + bv;
                if (RELU) v = fmaxf(v, 0.f);
                if (MODE == 0) {
                    C[(size_t)m * N + n] = v;
                } else if (MODE == 1) {
                    const int b = m >> 11, s = m & 2047;
                    const int h = n >> 6, d = n & 63;
                    C[((size_t)(b * PH + h) * PS + s) * PD + d] = v;
                } else if (MODE == 3) {
                    const int b = m >> 11, s = m & 2047;
                    const int h = n >> 6, d = n & 63;
                    Ohi[((size_t)(b * PH + h) * PS + s) * PD + d] = h16(v);
                } else if (MODE == 4) {
                    const int b = m >> 11;
                    const int h = n >> 6, d = n & 63;
                    const int scol = (m & 2047 & ~63) + ((mt & 1) << 5)
                                   + (lg << 3) + ((mt >> 1) << 2) + j;
                    Ohi[((size_t)(b * PH + h) * PD + d) * PS + scol] = h16(v);
                } else if (MODE == 5) {
                    const size_t idx = (size_t)m * N + n;
                    unsigned short hh, ll;
                    splith(v, hh, ll);
                    Ohi[idx] = hh; Olo[idx] = ll;
                } else { // MODE 6
                    const int b = m >> 11, s = m & 2047;
                    const int h = n >> 6, d = n & 63;
                    const float av = attn[((size_t)(b * PH + h) * PS + s) * PD + d];
                    const float o = (av * ascv + abiv) * (1.f + v * gain);
                    const size_t idx = (size_t)m * N + n;
                    unsigned short hh, ll;
                    splith(o, hh, ll);
                    Ohi[idx] = hh; Olo[idx] = ll;
                }
            }
        }
    }
}

// ---------------------------------------------------------------------------
// fp32-fed fallback GEMM (bf16 3-term internally, round-5 proven skeleton);
// MODE 3/4 emit fp16 single planes for the fp16 flash.
// ---------------------------------------------------------------------------
typedef __attribute__((ext_vector_type(8))) short short8;
#define MFMA16 __builtin_amdgcn_mfma_f32_16x16x32_bf16
__device__ inline unsigned short bf16rn(float x) {
    unsigned u = __builtin_bit_cast(unsigned, x);
    u += 0x7FFFu + ((u >> 16) & 1u);
    return (unsigned short)(u >> 16);
}
__device__ inline float bf16tof(unsigned short h) {
    unsigned u = ((unsigned)h) << 16;
    return __builtin_bit_cast(float, u);
}
__device__ inline void split2(float x, unsigned short& h, unsigned short& l) {
    h = bf16rn(x);
    l = bf16rn(x - bf16tof(h));
}

template<int MODE, bool RELU>
__global__ __launch_bounds__(256, 2)
void gemm_nt(const float* __restrict__ A, const float* __restrict__ Bw,
             const float* __restrict__ bias, float* __restrict__ C,
             unsigned short* __restrict__ Ohi,
             int M, int N, int K,
             const float* __restrict__ attn,
             const float* __restrict__ g0, const float* __restrict__ g1,
             const float* __restrict__ g2, const float* __restrict__ g3,
             const float* __restrict__ asc, const float* __restrict__ abi)
{
    __shared__ int4 ldsq[4096];
    char* const lds = (char*)ldsq;

    const int tid  = threadIdx.x;
    const int lane = tid & 63;
    const int w    = tid >> 6;
    const int lq   = lane & 15;
    const int lg   = lane >> 4;
    const int wm   = (w >> 1) * 64;
    const int wn   = (w & 1) * 64;
    const int m0   = blockIdx.x * 128;
    const int n0   = blockIdx.y * 128;

    const int irow = tid >> 3;
    const int ic8  = (tid & 7) * 8;
    const int woff = (ic8 * 2);

    f32x4 acc[4][4];
    #pragma unroll
    for (int mt = 0; mt < 4; ++mt)
        #pragma unroll
        for (int nt = 0; nt < 4; ++nt)
            acc[mt][nt] = (f32x4){0.f, 0.f, 0.f, 0.f};

    for (int k0 = 0; k0 < K; k0 += 64) {
        #pragma unroll
        for (int mat = 0; mat < 2; ++mat) {
            const float* const src = mat ? Bw : A;
            const int rbase = mat ? n0 : m0;
            const int pbase = mat ? 32768 : 0;
            #pragma unroll
            for (int r = 0; r < 4; ++r) {
                const int row = irow + 32 * r;
                const float* p = src + (size_t)(rbase + row) * K + k0 + ic8;
                float4 f0 = *(const float4*)p;
                float4 f1 = *(const float4*)(p + 4);
                short8 vh, vl;
                {
                    unsigned short h, l;
                    split2(f0.x, h, l); vh[0] = (short)h; vl[0] = (short)l;
                    split2(f0.y, h, l); vh[1] = (short)h; vl[1] = (short)l;
                    split2(f0.z, h, l); vh[2] = (short)h; vl[2] = (short)l;
                    split2(f0.w, h, l); vh[3] = (short)h; vl[3] = (short)l;
                    split2(f1.x, h, l); vh[4] = (short)h; vl[4] = (short)l;
                    split2(f1.y, h, l); vh[5] = (short)h; vl[5] = (short)l;
                    split2(f1.z, h, l); vh[6] = (short)h; vl[6] = (short)l;
                    split2(f1.w, h, l); vh[7] = (short)h; vl[7] = (short)l;
                }
                const int off = row * 128 + (woff ^ ((row & 7) << 4));
                *(short8*)(lds + pbase + off)         = vh;
                *(short8*)(lds + pbase + 16384 + off) = vl;
            }
        }
        __syncthreads();

        #pragma unroll
        for (int kh = 0; kh < 2; ++kh) {
            short8 afh[4], afl[4];
            #pragma unroll
            for (int mt = 0; mt < 4; ++mt) {
                const int row = wm + 16 * mt + lq;
                const int off = row * 128 + ((kh * 64 + 16 * lg) ^ ((row & 7) << 4));
                afh[mt] = *(const short8*)(lds + off);
                afl[mt] = *(const short8*)(lds + 16384 + off);
            }
            #pragma unroll
            for (int nt = 0; nt < 4; ++nt) {
                const int row = wn + 16 * nt + lq;
                const int off = row * 128 + ((kh * 64 + 16 * lg) ^ ((row & 7) << 4));
                short8 bfh = *(const short8*)(lds + 32768 + off);
                short8 bfl = *(const short8*)(lds + 49152 + off);
                #pragma unroll
                for (int mt = 0; mt < 4; ++mt) {
                    acc[mt][nt] = MFMA16(afh[mt], bfh, acc[mt][nt], 0, 0, 0);
                    acc[mt][nt] = MFMA16(afh[mt], bfl, acc[mt][nt], 0, 0, 0);
                    acc[mt][nt] = MFMA16(afl[mt], bfh, acc[mt][nt], 0, 0, 0);
                }
            }
        }
        __syncthreads();
    }

    float gain = 0.f, ascv = 0.f, abiv = 0.f;
    if (MODE == 2) {
        gain = 0.25f * (*g0 + *g1 + *g2 + *g3);
        ascv = *asc;
        abiv = *abi;
    }

    #pragma unroll
    for (int nt = 0; nt < 4; ++nt) {
        const int n  = n0 + wn + 16 * nt + lq;
        const float bv = bias[n];
        #pragma unroll
        for (int mt = 0; mt < 4; ++mt) {
            #pragma unroll
            for (int j = 0; j < 4; ++j) {
                const int m = m0 + wm + 16 * mt + 4 * lg + j;
                float v = acc[mt][nt][j] + bv;
                if (RELU) v = fmaxf(v, 0.f);
                if (MODE == 0) {
                    C[(size_t)m * N + n] = v;
                } else if (MODE == 1) {
                    const int b = m >> 11, s = m & 2047;
                    const int h = n >> 6, d = n & 63;
                    C[((size_t)(b * PH + h) * PS + s) * PD + d] = v;
                } else if (MODE == 3) {
                    const int b = m >> 11, s = m & 2047;
                    const int h = n >> 6, d = n & 63;
                    Ohi[((size_t)(b * PH + h) * PS + s) * PD + d] = h16(v);
                } else if (MODE == 4) {
                    const int b = m >> 11;
                    const int h = n >> 6, d = n & 63;
                    const int scol = (m & 2047 & ~63) + ((mt & 1) << 5)
                                   + (lg << 3) + ((mt >> 1) << 2) + j;
                    Ohi[((size_t)(b * PH + h) * PD + d) * PS + scol] = h16(v);
                } else { // MODE 2
                    const int b = m >> 11, s = m & 2047;
                    const int h = n >> 6, d = n & 63;
                    const float av = attn[((size_t)(b * PH + h) * PS + s) * PD + d];
                    C[(size_t)m * N + n] = (av * ascv + abiv) * (1.f + v * gain);
                }
            }
        }
    }
}

// ---------------------------------------------------------------------------
// MFMA flash attention v7 (fp16): K and V^T single fp16 planes, Q split
// fp16 hi/lo (2-term QK^T = 4 MFMA/mt/u-pair), P in fp16 (RNE), PV 1 MFMA,
// l via MFMA(ones,P). 32KB double-buffer, 2 blocks/CU, gload_lds staging
// with pre-swizzled source, XCD swizzle, defer-max. 52 MFMA/tile/wave.
// ---------------------------------------------------------------------------
__global__ __launch_bounds__(256, 2)
void flash_mfma(const float* qf,
                const unsigned short* __restrict__ kf,
                const unsigned short* __restrict__ vtf,
                float* attn)
{
    __shared__ int4 ldsv[2048];                    // 32 KB: 2 bufs x (K8K + V8K)
    char* const ldsb = (char*)ldsv;

    const int tid  = threadIdx.x;
    const int lane = tid & 63;
    const int w    = tid >> 6;
    const int lq   = lane & 15;
    const int lg   = lane >> 4;

    // XCD swizzle: each XCD owns 128 consecutive logical blocks (= 8 bh).
    const int L  = blockIdx.x + (blockIdx.y << 4) + (blockIdx.z << 8);
    const int nL = ((L & 7) << 7) + (L >> 3);
    const int bh = nL >> 4;
    const int q0 = (nL & 15) * 128 + w * 32;

    const size_t kbase = (size_t)bh * PS * PD;   // K rows   [S][D]
    const size_t vbase = (size_t)bh * PD * PS;   // V^T rows [D][S] (permuted)

    const unsigned short* const gp = (w < 2) ? kf + kbase : vtf + vbase;
    const bool isK = (w < 2);
    const int ch0   = (w & 1) * 4;
    const int scol8 = (((lane & 7) ^ (lane >> 3)) << 3);   // pre-swizzled col
    const int lrow8 = lane >> 3;

    auto ISSUE = [&](int kt, int bufn) {
        #pragma unroll
        for (int r = 0; r < 4; ++r) {
            const int c   = ch0 + r;
            const int row = c * 8 + lrow8;
            const size_t goff = isK ? (size_t)(kt + row) * PD + scol8
                                    : (size_t)row * PS + kt + scol8;
            GLOAD_LDS(gp + goff,
                      ldsb + bufn * 16384 + (isK ? 0 : 8192) + c * 1024 + 16 * lane);
        }
    };

    const half8 onesh = {(_Float16)1.f, (_Float16)1.f, (_Float16)1.f,
                         (_Float16)1.f, (_Float16)1.f, (_Float16)1.f,
                         (_Float16)1.f, (_Float16)1.f};

    // ---- Q fragments (scale 1/8 folded in), fp16 hi/lo, 2 q-subtiles
    half8 qh[2][2], ql[2][2];
    #pragma unroll
    for (int u = 0; u < 2; ++u) {
        const float* qp = qf + ((size_t)bh * PS + q0 + 16 * u + lq) * PD + 8 * lg;
        #pragma unroll
        for (int t = 0; t < 2; ++t)
            #pragma unroll
            for (int b = 0; b < 8; ++b) {
                float x = qp[t * 32 + b] * 0.125f;
                _Float16 hh = (_Float16)x;
                qh[u][t][b] = hh;
                ql[u][t][b] = (_Float16)(x - (float)hh);
            }
    }

    f32x4 ot[2][4];
    #pragma unroll
    for (int u = 0; u < 2; ++u)
        #pragma unroll
        for (int mt = 0; mt < 4; ++mt)
            ot[u][mt] = (f32x4){0.f, 0.f, 0.f, 0.f};
    f32x4 lacc[2] = {{0.f,0.f,0.f,0.f}, {0.f,0.f,0.f,0.f}};
    float m_run[2] = {-3.0e38f, -3.0e38f};

    ISSUE(0, 0);
    __syncthreads();

    int buf = 0;
    for (int kti = 0; kti < PS / 64; ++kti) {
        const bool pf = (kti + 1 < PS / 64);
        if (pf) ISSUE((kti + 1) * 64, buf ^ 1);

        const char* const L2 = ldsb + buf * 16384;

        // ---- S^T tiles (2-term: K single x Q hi/lo)
        f32x4 st[2][4];
        #pragma unroll
        for (int mt = 0; mt < 4; ++mt) {
            const int row = 16 * mt + lq;
            const int swz = (row & 7) << 4;
            const char* kr = L2 + row * 128;
            half8 a0 = *(const half8*)(kr + ((16 * lg) ^ swz));
            half8 a1 = *(const half8*)(kr + ((64 + 16 * lg) ^ swz));
            #pragma unroll
            for (int u = 0; u < 2; ++u) {
                f32x4 acc = {0.f, 0.f, 0.f, 0.f};
                acc = MFMAH(a0, qh[u][0], acc, 0, 0, 0);
                acc = MFMAH(a1, qh[u][1], acc, 0, 0, 0);
                acc = MFMAH(a0, ql[u][0], acc, 0, 0, 0);
                acc = MFMAH(a1, ql[u][1], acc, 0, 0, 0);
                st[u][mt] = acc;
            }
        }

        // ---- online softmax (defer-max) + P pack (fp16 RNE) + l via MFMA
        half8 pb[2][2];
        #pragma unroll
        for (int u = 0; u < 2; ++u) {
            float pmax = -3.0e38f;
            #pragma unroll
            for (int mt = 0; mt < 4; ++mt)
                #pragma unroll
                for (int j = 0; j < 4; ++j)
                    pmax = fmaxf(pmax, st[u][mt][j]);
            pmax = fmaxf(pmax, __shfl_xor(pmax, 16));
            pmax = fmaxf(pmax, __shfl_xor(pmax, 32));
            if (!__all(pmax - m_run[u] <= 8.f)) {   // rare: rescale path
                float mnew = fmaxf(m_run[u], pmax);
                float corr = __expf(m_run[u] - mnew);
                m_run[u] = mnew;
                #pragma unroll
                for (int j = 0; j < 4; ++j)
                    lacc[u][j] *= corr;
                #pragma unroll
                for (int mt = 0; mt < 4; ++mt)
                    #pragma unroll
                    for (int j = 0; j < 4; ++j)
                        ot[u][mt][j] *= corr;
            }
            #pragma unroll
            for (int mt = 0; mt < 4; ++mt)
                #pragma unroll
                for (int j = 0; j < 4; ++j)
                    st[u][mt][j] = __expf(st[u][mt][j] - m_run[u]);
            // pb[u][t][b] = fp16(st[u][(b>>2)*2+t][b&3])
            #pragma unroll
            for (int t = 0; t < 2; ++t)
                #pragma unroll
                for (int b = 0; b < 8; ++b)
                    pb[u][t][b] = (_Float16)st[u][(b >> 2) * 2 + t][b & 3];
            lacc[u] = MFMAH(onesh, pb[u][0], lacc[u], 0, 0, 0);
            lacc[u] = MFMAH(onesh, pb[u][1], lacc[u], 0, 0, 0);
        }

        // ---- O^T += V^T . P^T   (V single fp16, P fp16: 1 MFMA each)
        #pragma unroll
        for (int t = 0; t < 2; ++t) {
            #pragma unroll
            for (int mt = 0; mt < 4; ++mt) {
                const int row = 16 * mt + lq;
                const int swz = (row & 7) << 4;
                const char* vr = L2 + 8192 + row * 128;
                half8 vv = *(const half8*)(vr + ((t * 64 + 16 * lg) ^ swz));
                #pragma unroll
                for (int u = 0; u < 2; ++u)
                    ot[u][mt] = MFMAH(vv, pb[u][t], ot[u][mt], 0, 0, 0);
            }
        }

        __syncthreads();        // drains prefetch vmcnt + protects LDS reuse
        buf ^= 1;
    }

    // ---- epilogue: attn[bh][q0+16u+lq][d], d = 16*mt + 4*lg + j
    #pragma unroll
    for (int u = 0; u < 2; ++u) {
        const float inv = 1.f / lacc[u][0];
        float* op = attn + ((size_t)bh * PS + q0 + 16 * u + lq) * PD + 4 * lg;
        #pragma unroll
        for (int mt = 0; mt < 4; ++mt) {
            float4 o;
            o.x = ot[u][mt][0] * inv; o.y = ot[u][mt][1] * inv;
            o.z = ot[u][mt][2] * inv; o.w = ot[u][mt][3] * inv;
            *(float4*)(op + 16 * mt) = o;
        }
    }
}

// ---------------------------------------------------------------------------
extern "C" void kernel_launch(void* const* d_in, const int* in_sizes, int n_in,
                              void* d_out, int out_size, void* d_ws, size_t ws_size,
                              hipStream_t stream)
{
    const float* query = (const float*)d_in[0];
    const float* Wq  = (const float*)d_in[1];  const float* bq  = (const float*)d_in[2];
    const float* Wk  = (const float*)d_in[3];  const float* bk  = (const float*)d_in[4];
    const float* Wv  = (const float*)d_in[5];  const float* bv  = (const float*)d_in[6];
    const float* Wo  = (const float*)d_in[7];  const float* bo  = (const float*)d_in[8];
    const float* Wm1 = (const float*)d_in[9];  const float* bm1 = (const float*)d_in[10];
    const float* Wm2 = (const float*)d_in[11]; const float* bm2 = (const float*)d_in[12];
    const float* dop = (const float*)d_in[13];
    const float* ser = (const float*)d_in[14];
    const float* nor = (const float*)d_in[15];
    const float* ach = (const float*)d_in[16];
    const float* asc = (const float*)d_in[17];
    const float* abi = (const float*)d_in[18];
    float* out = (float*)d_out;

    char* wsb = (char*)d_ws;
    // Common: qf32 [0,32M), kf fp16 [32M,48M), vtf fp16 [48M,64M)
    float*          qf32 = (float*)wsb;
    unsigned short* kf   = (unsigned short*)(wsb + (32u << 20));
    unsigned short* vtf  = (unsigned short*)(wsb + (48u << 20));

    dim3 blk(256);
    const bool presplit = (ws_size >= 161480704ull);             // 154 MB

    if (presplit) {
        unsigned short* h1hi  = (unsigned short*)(wsb + (64u << 20));  // 4MB
        unsigned short* h1lo  = (unsigned short*)(wsb + (68u << 20));  // 4MB
        unsigned short* afhi  = (unsigned short*)(wsb + (72u << 20));  // 16MB
        unsigned short* aflo  = (unsigned short*)(wsb + (88u << 20));  // 16MB
        unsigned short* qhi   = (unsigned short*)(wsb + (104u << 20)); // 16MB
        unsigned short* qlo   = (unsigned short*)(wsb + (120u << 20)); // 16MB
        unsigned short* wqh   = (unsigned short*)(wsb + (136u << 20)); // 2MB
        unsigned short* wkh   = (unsigned short*)(wsb + (138u << 20));
        unsigned short* wvh   = (unsigned short*)(wsb + (140u << 20));
        unsigned short* woh   = (unsigned short*)(wsb + (142u << 20));
        unsigned short* m1h   = (unsigned short*)(wsb + (144u << 20)); // 0.5MB
        unsigned short* m2h   = (unsigned short*)(wsb + (145u << 20));

        split_all<<<12800, blk, 0, stream>>>(
            query, Wq, Wk, Wv, Wo, Wm1, Wm2,
            qhi, qlo, wqh, wkh, wvh, woh, m1h, m2h);

        gemm_pl<1, false><<<dim3(PM / 128, PE / 128), blk, 0, stream>>>(
            qhi, qlo, wqh, bq, qf32, nullptr, nullptr, PM, PE, PE,
            nullptr, nullptr, nullptr, nullptr, nullptr, nullptr, nullptr);
        gemm_pl<3, false><<<dim3(PM / 128, PE / 128), blk, 0, stream>>>(
            qhi, qlo, wkh, bk, nullptr, kf, nullptr, PM, PE, PE,
            nullptr, nullptr, nullptr, nullptr, nullptr, nullptr, nullptr);
        gemm_pl<4, false><<<dim3(PM / 128, PE / 128), blk, 0, stream>>>(
            qhi, qlo, wvh, bv, nullptr, vtf, nullptr, PM, PE, PE,
            nullptr, nullptr, nullptr, nullptr, nullptr, nullptr, nullptr);
        gemm_pl<5, true><<<dim3(PM / 128, 256 / 128), blk, 0, stream>>>(
            qhi, qlo, m1h, bm1, nullptr, h1hi, h1lo, PM, 256, PE,
            nullptr, nullptr, nullptr, nullptr, nullptr, nullptr, nullptr);

        flash_mfma<<<dim3(PS / 128, PH, PB), blk, 0, stream>>>(
            qf32, kf, vtf, qf32);

        gemm_pl<6, false><<<dim3(PM / 128, PE / 128), blk, 0, stream>>>(
            h1hi, h1lo, m2h, bm2, nullptr, afhi, aflo, PM, PE, 256,
            qf32, dop, ser, nor, ach, asc, abi);
        gemm_pl<0, false><<<dim3(PM / 128, PE / 128), blk, 0, stream>>>(
            afhi, aflo, woh, bo, out, nullptr, nullptr, PM, PE, PE,
            nullptr, nullptr, nullptr, nullptr, nullptr, nullptr, nullptr);
    } else {
        // fallback: fp32-fed bf16 3-term GEMMs + fp16 flash
        float* h1    = (float*)(wsb + (64u << 20));   // 8MB
        float* attnf = (float*)(wsb + (72u << 20));   // 32MB

        gemm_nt<1, false><<<dim3(PM / 128, PE / 128), blk, 0, stream>>>(
            query, Wq, bq, qf32, nullptr, PM, PE, PE,
            nullptr, nullptr, nullptr, nullptr, nullptr, nullptr, nullptr);
        gemm_nt<3, false><<<dim3(PM / 128, PE / 128), blk, 0, stream>>>(
            query, Wk, bk, nullptr, kf, PM, PE, PE,
            nullptr, nullptr, nullptr, nullptr, nullptr, nullptr, nullptr);
        gemm_nt<4, false><<<dim3(PM / 128, PE / 128), blk, 0, stream>>>(
            query, Wv, bv, nullptr, vtf, PM, PE, PE,
            nullptr, nullptr, nullptr, nullptr, nullptr, nullptr, nullptr);
        gemm_nt<0, true><<<dim3(PM / 128, 256 / 128), blk, 0, stream>>>(
            query, Wm1, bm1, h1, nullptr, PM, 256, PE,
            nullptr, nullptr, nullptr, nullptr, nullptr, nullptr, nullptr);

        flash_mfma<<<dim3(PS / 128, PH, PB), blk, 0, stream>>>(
            qf32, kf, vtf, qf32);

        gemm_nt<2, false><<<dim3(PM / 128, PE / 128), blk, 0, stream>>>(
            h1, Wm2, bm2, attnf, nullptr, PM, PE, 256,
            qf32, dop, ser, nor, ach, asc, abi);
        gemm_nt<0, false><<<dim3(PM / 128, PE / 128), blk, 0, stream>>>(
            attnf, Wo, bo, out, nullptr, PM, PE, PE,
            nullptr, nullptr, nullptr, nullptr, nullptr, nullptr, nullptr);
    }
}